// Round 15
// baseline (168.195 us; speedup 1.0000x reference)
//
#include <hip/hip_runtime.h>
#include <hip/hip_bf16.h>

#define SS 30
#define DD 14
#define MM 28

// Per-batch LDS float offsets (PB = 1844 fl = 7,376 B; block = 2 batches = 14,752 B)
#define HX  0     // 435: xn fp32(420) -> h bf16 stride29 (870us) -> y_m fp32(420)
#define CQ  436   // 640: c bf16 32x40us -> yn fp32(420) -> tanh(y_s)(420)
#define UE  1076  // 640: ul bf16 -> vb frags(2048B) -> e bf16 -> gx(240) -> UV(90)
#define ST2 1716  // 64: gif -> G0 stats stride2 -> hs(60) -> M partials(64)
#define EA  1780  // 32: exp(a_s), pads 30,31 = 0
#define ECM 1812  // 32: exp(-cm_t), pads = 0 -> inv (G0)
#define PB  1844

typedef short bshort8 __attribute__((ext_vector_type(8)));
typedef float f32x16 __attribute__((ext_vector_type(16)));

union __align__(16) FragU { unsigned int u[4]; bshort8 v; };

__device__ __forceinline__ float frcp(float v){ return __builtin_amdgcn_rcpf(v); }
__device__ __forceinline__ float frsq(float v){ return __builtin_amdgcn_rsqf(v); }
__device__ __forceinline__ float fsigm(float v){ return frcp(1.f+__expf(-v)); }
__device__ __forceinline__ float fsilu(float v){ return v*frcp(1.f+__expf(-v)); }
__device__ __forceinline__ float ftanh_(float v){
    float c = fminf(fmaxf(v, -15.f), 15.f);
    float e = __expf(2.f*c);
    return (e-1.f)*frcp(e+1.f);
}
__device__ __forceinline__ float fgelu(float v){
    float t = ftanh_(0.7978845608028654f*(v + 0.044715f*v*v*v));
    return 0.5f*v*(1.f+t);
}
__device__ __forceinline__ unsigned int pkbf(float a, float b){
    __hip_bfloat162 h = __float22bfloat162_rn(make_float2(a,b));
    return *reinterpret_cast<unsigned int*>(&h);
}
__device__ __forceinline__ unsigned short bfr(float f){
    __hip_bfloat16 h = __float2bfloat16(f);
    return *reinterpret_cast<unsigned short*>(&h);
}
__device__ __forceinline__ float lobf(unsigned int u){ return __uint_as_float(u<<16); }
__device__ __forceinline__ float hibf(unsigned int u){ return __uint_as_float(u & 0xFFFF0000u); }

__device__ __forceinline__ void load_wfrag(const float* __restrict__ W,
                                           const float* __restrict__ bias, float scale,
                                           int ncol, int lo, int hi, FragU& o0, FragU& o1){
    float t[16];
    #pragma unroll
    for (int sl=0; sl<2; sl++){
        #pragma unroll
        for (int r=0;r<8;r++){
            int h = 8*hi + r + 16*sl;
            float v = 0.f;
            if (lo < ncol){
                if (h < MM) v = W[h*ncol+lo]*scale;
                else if (h == MM) v = bias[lo]*scale;
            }
            t[sl*8+r] = v;
        }
    }
    #pragma unroll
    for (int p=0;p<4;p++){
        o0.u[p] = pkbf(t[2*p],   t[2*p+1]);
        o1.u[p] = pkbf(t[8+2*p], t[8+2*p+1]);
    }
}

__device__ __forceinline__ void asm_frag(const f32x16& d, int hi, FragU& s0, FragU& s1){
    unsigned int P[8], X[8];
    #pragma unroll
    for (int m=0;m<8;m++) P[m] = pkbf(d[2*m], d[2*m+1]);
    #pragma unroll
    for (int m=0;m<8;m++) X[m] = (unsigned int)__shfl_xor((int)P[m], 32, 64);
    s0.u[0] = hi ? X[2] : P[0];  s0.u[1] = hi ? X[3] : P[1];
    s0.u[2] = hi ? P[2] : X[0];  s0.u[3] = hi ? P[3] : X[1];
    s1.u[0] = hi ? X[6] : P[4];  s1.u[1] = hi ? X[7] : P[5];
    s1.u[2] = hi ? P[6] : X[4];  s1.u[3] = hi ? P[7] : X[5];
}

extern "C" __global__ void __launch_bounds__(256, 8)
net_kernel(const float* __restrict__ xg,
           const float* __restrict__ ln_g, const float* __restrict__ ln_b,
           const float* __restrict__ Wup_l, const float* __restrict__ bup_l,
           const float* __restrict__ Wup_r, const float* __restrict__ bup_r,
           const float* __restrict__ conv_w, const float* __restrict__ conv_b,
           const float* __restrict__ Wq, const float* __restrict__ bq,
           const float* __restrict__ Wk, const float* __restrict__ bk,
           const float* __restrict__ Wv, const float* __restrict__ bv,
           const float* __restrict__ Wif, const float* __restrict__ bif,
           const float* __restrict__ gn_g, const float* __restrict__ gn_b,
           const float* __restrict__ skip,
           const float* __restrict__ Wdown, const float* __restrict__ bdown,
           const float* __restrict__ s_ln_g, const float* __restrict__ s_ln_b,
           const float* __restrict__ sW, const float* __restrict__ sR, const float* __restrict__ sb,
           const float* __restrict__ s_gn_g, const float* __restrict__ s_gn_b,
           const float* __restrict__ sWup1, const float* __restrict__ sbup1,
           const float* __restrict__ sWup2, const float* __restrict__ sbup2,
           const float* __restrict__ sWdown, const float* __restrict__ sbdown,
           const float* __restrict__ fc1w, const float* __restrict__ fc1b,
           const float* __restrict__ fc3w, const float* __restrict__ fc3b,
           float* __restrict__ out)
{
    __shared__ __align__(16) float smAll[2*PB];
    const int tid  = threadIdx.x;
    const int wid  = tid >> 6;
    const int lane = tid & 63;
    const int pbch = wid >> 1;       // batch within block
    const int hw   = wid & 1;        // half-role within batch pair
    const int b = blockIdx.x*2 + pbch;
    float* sm = smAll + pbch*PB;
    unsigned short* smu = reinterpret_cast<unsigned short*>(sm);
    char* smc = reinterpret_cast<char*>(sm);
    const float* xp = xg + (size_t)b * (SS*DD);

    const int lo = lane & 31, hi = lane >> 5;
    const int jq = lane % MM;
    const int g2 = lane / MM;        // 0/1 for lane<56
    const bool act = lane < 56;
    const int jqi = act ? jq : 0;
    const int t0 = hw*15;

    // ---- pads (wave A of each pair) ----
    if (hw == 0){
        if (lane < SS){
            *(uint2*)(smc + CQ*4 + lane*80 + 56) = make_uint2(0x3F80u, 0u);
            *(uint2*)(smc + UE*4 + lane*80 + 56) = make_uint2(0x3F80u, 0u);
        }
        if (lane < 20){
            *(uint2*)(smc + CQ*4 + 30*80 + lane*8) = make_uint2(0u,0u);
            *(uint2*)(smc + UE*4 + 30*80 + lane*8) = make_uint2(0u,0u);
        }
    }

    // ---- VALU weight preloads (B/C) ----
    float wl[DD], cw[4];
    float blr, cbr;
    {
        #pragma unroll
        for (int d=0; d<DD; d++) wl[d] = Wup_l[d*MM+jqi];
        #pragma unroll
        for (int k=0; k<4; k++) cw[k] = conv_w[k*MM+jqi];
        blr = bup_l[jqi]; cbr = conv_b[jqi];
    }

    // ---- Phase A: LN1 -> xn (each wave its 15 t's) ----
    if (lane < 15){
        int t = t0 + lane;
        float xv[DD];
        const float2* xr = (const float2*)(xp + t*DD);
        float s=0.f, s2=0.f;
        #pragma unroll
        for (int u=0;u<7;u++){ float2 f=xr[u]; xv[2*u]=f.x; xv[2*u+1]=f.y; s+=f.x+f.y; s2+=f.x*f.x+f.y*f.y; }
        float mu=s*(1.f/DD), var=s2*(1.f/DD)-mu*mu, rsg=frsq(var+1e-5f);
        #pragma unroll
        for (int d=0; d<DD; d++) sm[HX+t*DD+d] = (xv[d]-mu)*rsg*ln_g[d]+ln_b[d];
    }
    __syncthreads();

    // ---- Phase B: ul = xn @ Wup_l + bup_l -> ul bf16 (UE) ----
    #pragma unroll
    for (int k=0; k<8; k++){
        int tt = g2*8 + k;
        if (act && tt < 15){
            int t = t0 + tt;
            const float2* xr = (const float2*)&sm[HX + t*DD];
            float a = blr;
            #pragma unroll
            for (int u=0;u<7;u++){ float2 f = xr[u]; a += f.x*wl[2*u] + f.y*wl[2*u+1]; }
            smu[UE*2 + t*40 + jq] = bfr(a);
        }
    }
    __syncthreads();

    // ---- Phase C: conv + silu -> c bf16 (reads ul bf16) ----
    #pragma unroll
    for (int k=0; k<8; k++){
        int tt = g2*8 + k;
        if (act && tt < 15){
            int t = t0 + tt;
            float a = cbr;
            #pragma unroll
            for (int kk=0;kk<4;kk++){
                int ts = t-3+kk;
                if (ts>=0) a += lobf((unsigned int)smu[UE*2 + ts*40 + jq])*cw[kk];
            }
            smu[CQ*2 + t*40 + jq] = bfr(fsilu(a));
        }
    }
    __syncthreads();

    // ---- gif = c(bf16) @ Wif + bif -> ST2 (each wave its 15 t's) ----
    if (lane < 30){
        int t = t0 + (lane>>1), gg = lane&1;
        float a = bif[gg];
        const uint2* cr = (const uint2*)(smc + CQ*4 + t*80);
        #pragma unroll
        for (int p=0;p<7;p++){
            uint2 cu = cr[p];
            a += lobf(cu.x)*Wif[(4*p)*2+gg]   + hibf(cu.x)*Wif[(4*p+1)*2+gg]
               + lobf(cu.y)*Wif[(4*p+2)*2+gg] + hibf(cu.y)*Wif[(4*p+3)*2+gg];
        }
        sm[ST2 + t*2 + gg] = a;
    }
    __syncthreads();

    // ---- D3: gate pre-scan (wave A only) -> EA, ECM ----
    if (hw == 0){
        if (lane < SS){
            float i_ = sm[ST2+2*lane], f_ = sm[ST2+2*lane+1];
            float F = f_, v;
            v = __shfl_up(F,1,64);  if (lane>=1)  F += v;
            v = __shfl_up(F,2,64);  if (lane>=2)  F += v;
            v = __shfl_up(F,4,64);  if (lane>=4)  F += v;
            v = __shfl_up(F,8,64);  if (lane>=8)  F += v;
            v = __shfl_up(F,16,64); if (lane>=16) F += v;
            float a = i_ - F;
            float cm = a;
            v = __shfl_up(cm,1,64);  if (lane>=1)  cm = fmaxf(cm,v);
            v = __shfl_up(cm,2,64);  if (lane>=2)  cm = fmaxf(cm,v);
            v = __shfl_up(cm,4,64);  if (lane>=4)  cm = fmaxf(cm,v);
            v = __shfl_up(cm,8,64);  if (lane>=8)  cm = fmaxf(cm,v);
            v = __shfl_up(cm,16,64); if (lane>=16) cm = fmaxf(cm,v);
            cm = fmaxf(cm, 0.f);
            sm[EA+lane]  = __expf(a);
            sm[ECM+lane] = __expf(-cm);
        } else if (lane < 32){
            sm[EA+lane] = 0.f; sm[ECM+lane] = 0.f;
        }
    }
    // ---- silu(ur) precompute for this wave's 15 t's (4 packed regs) ----
    unsigned int urp[4];
    {
        float wr[DD], brr = bup_r[jqi];
        #pragma unroll
        for (int d=0;d<DD;d++) wr[d]=Wup_r[d*MM+jqi];
        float slv[8];
        #pragma unroll
        for (int k=0; k<8; k++){
            int tt = g2*8 + k;
            float a = brr;
            if (act && tt < 15){
                int t = t0 + tt;
                const float2* xr = (const float2*)&sm[HX + t*DD];
                #pragma unroll
                for (int u=0;u<7;u++){ float2 f=xr[u]; a += f.x*wr[2*u]+f.y*wr[2*u+1]; }
            }
            slv[k] = fsilu(a);
        }
        #pragma unroll
        for (int p=0;p<4;p++) urp[p] = pkbf(slv[2*p], slv[2*p+1]);
    }
    __syncthreads();

    // ================= MFMA: wave A = q,k,scores; wave B = v =================
    FragU fa0, fa1;        // wave A: score frags
    FragU wd0, wd1;        // wave B: Wdown frags (loaded in slack)
    if (hw == 0){
        FragU cf0 = *(const FragU*)(smc + CQ*4 + lo*80 + hi*16);
        FragU cf1 = *(const FragU*)(smc + CQ*4 + lo*80 + hi*16 + 32);
        FragU eq0, eq1, ek0, ek1;
        {
            FragU wq0, wq1;
            load_wfrag(Wq, bq, 1.f, MM, lo, hi, wq0, wq1);
            f32x16 aq = {};
            aq = __builtin_amdgcn_mfma_f32_32x32x16_bf16(wq0.v, cf0.v, aq, 0,0,0);
            aq = __builtin_amdgcn_mfma_f32_32x32x16_bf16(wq1.v, cf1.v, aq, 0,0,0);
            asm_frag(aq, hi, eq0, eq1);
        }
        {
            const float rs28 = 0.18898223650461363f;
            FragU wk0, wk1;
            load_wfrag(Wk, bk, rs28, MM, lo, hi, wk0, wk1);
            f32x16 ak = {};
            ak = __builtin_amdgcn_mfma_f32_32x32x16_bf16(wk0.v, cf0.v, ak, 0,0,0);
            ak = __builtin_amdgcn_mfma_f32_32x32x16_bf16(wk1.v, cf1.v, ak, 0,0,0);
            asm_frag(ak, hi, ek0, ek1);
        }
        {
            f32x16 es = {};
            es = __builtin_amdgcn_mfma_f32_32x32x16_bf16(ek0.v, eq0.v, es, 0,0,0);
            es = __builtin_amdgcn_mfma_f32_32x32x16_bf16(ek1.v, eq1.v, es, 0,0,0);
            float ecmt = sm[ECM + lo];
            #pragma unroll
            for (int g=0; g<16; g++){
                int srow = (g&3) + 8*(g>>2) + 4*hi;
                float w = sm[EA + srow] * ecmt;
                es[g] = (srow <= lo) ? es[g]*w : 0.f;
            }
            asm_frag(es, hi, fa0, fa1);
        }
    } else {
        FragU wv0, wv1;
        load_wfrag(Wv, bv, 1.f, MM, lo, hi, wv0, wv1);
        FragU uf0 = *(const FragU*)(smc + UE*4 + lo*80 + hi*16);
        FragU uf1 = *(const FragU*)(smc + UE*4 + lo*80 + hi*16 + 32);
        f32x16 av = {};
        av = __builtin_amdgcn_mfma_f32_32x32x16_bf16(uf0.v, wv0.v, av, 0,0,0);
        av = __builtin_amdgcn_mfma_f32_32x32x16_bf16(uf1.v, wv1.v, av, 0,0,0);
        FragU vb0, vb1;
        asm_frag(av, hi, vb0, vb1);
        if (lo == MM){
            const unsigned int ONE2 = 0x3F803F80u;
            vb0.u[0]=ONE2; vb0.u[1]=ONE2; vb0.u[2]=ONE2; vb0.u[3]=ONE2;
            vb1.u[0]=ONE2; vb1.u[1]=ONE2; vb1.u[2]=ONE2; vb1.u[3]= hi ? 0u : ONE2;
        }
        *(uint4*)(smc + UE*4 + lane*32)      = make_uint4(vb0.u[0],vb0.u[1],vb0.u[2],vb0.u[3]);
        *(uint4*)(smc + UE*4 + lane*32 + 16) = make_uint4(vb1.u[0],vb1.u[1],vb1.u[2],vb1.u[3]);
    }
    __syncthreads();

    if (hw == 0){
        FragU vb0, vb1;
        uint4 r0 = *(const uint4*)(smc + UE*4 + lane*32);
        uint4 r1 = *(const uint4*)(smc + UE*4 + lane*32 + 16);
        vb0.u[0]=r0.x; vb0.u[1]=r0.y; vb0.u[2]=r0.z; vb0.u[3]=r0.w;
        vb1.u[0]=r1.x; vb1.u[1]=r1.y; vb1.u[2]=r1.z; vb1.u[3]=r1.w;
        f32x16 hacc = {};
        hacc = __builtin_amdgcn_mfma_f32_32x32x16_bf16(fa0.v, vb0.v, hacc, 0,0,0);
        hacc = __builtin_amdgcn_mfma_f32_32x32x16_bf16(fa1.v, vb1.v, hacc, 0,0,0);
        #pragma unroll
        for (int g=0; g<16; g++){
            int trow = (g&3) + 8*(g>>2) + 4*hi;
            if (lo < 29 && trow < SS) smu[HX*2 + trow*29 + lo] = bfr(hacc[g]);
        }
    } else {
        load_wfrag(Wdown, bdown, 1.f, DD, lo, hi, wd0, wd1);  // for Phase H
    }
    __syncthreads();

    // ---- VALU preloads for G/L ----
    const int dq  = lane % DD;
    const int g4  = lane / DD;
    const int dqi = act ? dq : 0;
    float skr=skip[jqi], ggr=gn_g[jqi], gbr=gn_b[jqi];
    float swd0 = sWdown[0*DD+dqi], swd1 = sWdown[1*DD+dqi], swd2 = sWdown[2*DD+dqi];
    float sbd  = sbdown[dqi];

    // ---- Phase G0: per-t stats (each wave its 15 t's) ----
    if (lane < 15){
        int t = t0 + lane;
        float s=0.f,s2=0.f;
        #pragma unroll
        for (int u=0;u<MM;u++){
            float v = lobf((unsigned int)smu[HX*2 + t*29 + u]);
            s+=v; s2+=v*v;
        }
        float rsum = lobf((unsigned int)smu[HX*2 + t*29 + MM]);
        float inv = frcp(fmaxf(fabsf(rsum), 1.f));
        float mu=s*(1.f/MM), var=s2*(1.f/MM)-mu*mu;
        sm[ST2+t*2]   = mu*inv;
        sm[ST2+t*2+1] = frsq(var*inv*inv + 1e-5f);
        sm[ECM+t]     = inv;
    }
    __syncthreads();

    // ---- Phase G: e = (hn + skip*c)*silu_ur -> e bf16 (UE) + pad rewrite ----
    if (hw == 0){
        if (lane < SS) *(uint2*)(smc + UE*4 + lane*80 + 56) = make_uint2(0x3F80u, 0u);
    } else {
        if (lane < 20) *(uint2*)(smc + UE*4 + 30*80 + lane*8) = make_uint2(0u,0u);
    }
    #pragma unroll
    for (int k=0; k<8; k++){
        int tt = g2*8 + k;
        if (act && tt < 15){
            int t = t0 + tt;
            float inv = sm[ECM+t];
            float hv = lobf((unsigned int)smu[HX*2 + t*29 + jq])*inv;
            float hn = (hv-sm[ST2+t*2])*sm[ST2+t*2+1]*ggr + gbr;
            float cv = lobf((unsigned int)smu[CQ*2 + t*40 + jq]);
            float h2 = hn + skr*cv;
            float slu = (k&1) ? hibf(urp[k>>1]) : lobf(urp[k>>1]);
            smu[UE*2 + t*40 + jq] = bfr(h2 * slu);
        }
    }
    __syncthreads();

    // ---- Phase H (MFMA, wave B): y_m = e @ WdownAug + x -> HX fp32 ----
    if (hw == 1){
        FragU ef0 = *(const FragU*)(smc + UE*4 + lo*80 + hi*16);
        FragU ef1 = *(const FragU*)(smc + UE*4 + lo*80 + hi*16 + 32);
        f32x16 ym = {};
        ym = __builtin_amdgcn_mfma_f32_32x32x16_bf16(ef0.v, wd0.v, ym, 0,0,0);
        ym = __builtin_amdgcn_mfma_f32_32x32x16_bf16(ef1.v, wd1.v, ym, 0,0,0);
        #pragma unroll
        for (int g=0; g<16; g++){
            int trow = (g&3) + 8*(g>>2) + 4*hi;
            if (lo < DD && trow < SS) sm[HX + trow*DD + lo] = ym[g] + xp[trow*DD + lo];
        }
    }
    __syncthreads();

    // ---- Phase I: sLSTM LN -> yn fp32 into CQ (each wave its 15 t's) ----
    if (lane < 15){
        int t = t0 + lane;
        const float2* yr=(const float2*)&sm[HX+t*DD];
        float yv[DD];
        float s=0.f,s2=0.f;
        #pragma unroll
        for (int u=0;u<7;u++){ float2 f=yr[u]; yv[2*u]=f.x; yv[2*u+1]=f.y; s+=f.x+f.y; s2+=f.x*f.x+f.y*f.y; }
        float mu=s*(1.f/DD), var=s2*(1.f/DD)-mu*mu, rs=frsq(var+1e-5f);
        #pragma unroll
        for (int d=0;d<DD;d++)
            sm[CQ+t*DD+d] = (yv[d]-mu)*rs*s_ln_g[d] + s_ln_b[d];
    }
    __syncthreads();

    // ---- Phase J: gx = yn @ sW + sb -> UE (each wave 120 of 240) ----
    #pragma unroll
    for (int it=0; it<2; it++){
        int idx = lane + it*64;
        if (idx < 120){
            int t = t0 + (idx>>3), gg = idx&7;
            float a=sb[gg];
            const float2* yr = (const float2*)&sm[CQ+t*DD];
            #pragma unroll
            for (int u=0;u<7;u++){
                float2 f=yr[u];
                a += f.x*sW[(2*u)*8+gg] + f.y*sW[(2*u+1)*8+gg];
            }
            sm[UE + t*8 + gg] = a;
        }
    }
    __syncthreads();

    // ---- Phase K: sLSTM scan (wave A, lane0 writes hs -> ST2) ----
    if (hw == 0){
        float R0[8], R1[8];
        #pragma unroll
        for (int g=0; g<8; g++){ R0[g]=sR[g]; R1[g]=sR[8+g]; }
        float h0=0.f,h1=0.f,c0=0.f,c1=0.f,n0=0.f,n1=0.f,m0=0.f,m1=0.f;
        const float2* gr = (const float2*)&sm[UE];
        float2 A0=gr[0], A1=gr[1], A2=gr[2], A3=gr[3];
        #pragma unroll 1
        for (int t=0; t<SS; t++){
            float2 N0,N1,N2,N3;
            if (t < SS-1){
                const float2* nx = (const float2*)&sm[UE+(t+1)*8];
                N0=nx[0]; N1=nx[1]; N2=nx[2]; N3=nx[3];
            }
            float g0=A0.x+h0*R0[0]+h1*R1[0], g1=A0.y+h0*R0[1]+h1*R1[1];
            float g2v=A1.x+h0*R0[2]+h1*R1[2], g3=A1.y+h0*R0[3]+h1*R1[3];
            float g4v=A2.x+h0*R0[4]+h1*R1[4], g5=A2.y+h0*R0[5]+h1*R1[5];
            float g6=A3.x+h0*R0[6]+h1*R1[6], g7=A3.y+h0*R0[7]+h1*R1[7];
            float z0=ftanh_(g0), z1=ftanh_(g1);
            float mn0=fmaxf(g4v+m0, g2v), mn1=fmaxf(g5+m1, g3);
            float ie0=__expf(g2v-mn0), ie1=__expf(g3-mn1);
            float fe0=__expf(g4v+m0-mn0), fe1=__expf(g5+m1-mn1);
            c0 = fe0*c0 + ie0*z0;  c1 = fe1*c1 + ie1*z1;
            n0 = fe0*n0 + ie0;     n1 = fe1*n1 + ie1;
            h0 = c0*frcp((1.f+__expf(-g6))*n0);
            h1 = c1*frcp((1.f+__expf(-g7))*n1);
            m0 = mn0; m1 = mn1;
            if (lane == 0){ sm[ST2+t*2] = h0; sm[ST2+t*2+1] = h1; }
            A0=N0; A1=N1; A2=N2; A3=N3;
        }
    }
    __syncthreads();

    // ---- Phase L0: per-t u-values -> UE (each wave its 15 t's) ----
    if (lane < 15){
        int t = t0 + lane;
        float a0 = sm[ST2+t*2], a1 = sm[ST2+t*2+1];
        float mu = 0.5f*(a0+a1);
        float d0 = a0-mu, d1 = a1-mu;
        float var = 0.5f*(d0*d0 + d1*d1);
        float rsg = frsq(var + 1e-5f);
        float hn0 = d0*rsg*s_gn_g[0] + s_gn_b[0];
        float hn1 = d1*rsg*s_gn_g[1] + s_gn_b[1];
        #pragma unroll
        for (int u3=0; u3<3; u3++){
            float p1 = hn0*sWup1[u3] + hn1*sWup1[3+u3] + sbup1[u3];
            float p2 = hn0*sWup2[u3] + hn1*sWup2[3+u3] + sbup2[u3];
            sm[UE + t*3 + u3] = fgelu(p1)*p2;
        }
    }
    __syncthreads();

    // ---- Phase L: y_s + tanh -> CQ (each wave its 15 t's) ----
    #pragma unroll
    for (int tt=0; tt<4; tt++){
        int lt = g4 + 4*tt;
        if (act && lt < 15){
            int t = t0 + lt;
            float acc = sbd + sm[HX+t*DD+dq]
                      + sm[UE+t*3]*swd0 + sm[UE+t*3+1]*swd1 + sm[UE+t*3+2]*swd2;
            sm[CQ+t*DD+dq] = ftanh_(acc);
        }
    }
    __syncthreads();

    // ---- Phase M: head; each wave sums its 210 dims, combine via ST2 ----
    {
        int j = lane & 31, h2 = lane >> 5;
        const float2* tyr = (const float2*)&sm[CQ + hw*210];
        const float* w1 = fc1w + (hw*210)*32 + j;
        float a = 0.f;
        #pragma unroll 1
        for (int k=0; k<53; k++){
            int d2 = h2*53 + k;
            if (d2 < 105){
                float2 tv = tyr[d2];
                a += tv.x*w1[(2*d2)*32] + tv.y*w1[(2*d2+1)*32];
            }
        }
        a += __shfl_xor(a, 32, 64);
        if (lane < 32) sm[ST2 + hw*32 + lane] = a;
    }
    __syncthreads();
    if (hw == 0){
        int j = lane & 31;
        float a = sm[ST2 + j] + sm[ST2 + 32 + j] + fc1b[j];
        float r = fmaxf(a, 0.f);
        float p = r * fc3w[j];
        #pragma unroll
        for (int off=16; off>=1; off>>=1) p += __shfl_xor(p, off, 64);
        if (lane == 0) out[b] = p + fc3b[0];
    }
}

extern "C" void kernel_launch(void* const* d_in, const int* in_sizes, int n_in,
                              void* d_out, int out_size, void* d_ws, size_t ws_size,
                              hipStream_t stream) {
    const float* x      = (const float*)d_in[0];
    const float* ln_g   = (const float*)d_in[1];
    const float* ln_b   = (const float*)d_in[2];
    const float* Wup_l  = (const float*)d_in[3];
    const float* bup_l  = (const float*)d_in[4];
    const float* Wup_r  = (const float*)d_in[5];
    const float* bup_r  = (const float*)d_in[6];
    const float* conv_w = (const float*)d_in[7];
    const float* conv_b = (const float*)d_in[8];
    const float* Wq     = (const float*)d_in[9];
    const float* bq     = (const float*)d_in[10];
    const float* Wk     = (const float*)d_in[11];
    const float* bk     = (const float*)d_in[12];
    const float* Wv     = (const float*)d_in[13];
    const float* bv     = (const float*)d_in[14];
    const float* Wif    = (const float*)d_in[15];
    const float* bif    = (const float*)d_in[16];
    const float* gn_g   = (const float*)d_in[17];
    const float* gn_b   = (const float*)d_in[18];
    const float* skip   = (const float*)d_in[19];
    const float* Wdown  = (const float*)d_in[20];
    const float* bdown  = (const float*)d_in[21];
    const float* s_ln_g = (const float*)d_in[22];
    const float* s_ln_b = (const float*)d_in[23];
    const float* sW     = (const float*)d_in[24];
    const float* sR     = (const float*)d_in[25];
    const float* sb     = (const float*)d_in[26];
    const float* s_gn_g = (const float*)d_in[27];
    const float* s_gn_b = (const float*)d_in[28];
    const float* sWup1  = (const float*)d_in[29];
    const float* sbup1  = (const float*)d_in[30];
    const float* sWup2  = (const float*)d_in[31];
    const float* sbup2  = (const float*)d_in[32];
    const float* sWdown = (const float*)d_in[33];
    const float* sbdown = (const float*)d_in[34];
    const float* fc1w   = (const float*)d_in[35];
    const float* fc1b   = (const float*)d_in[36];
    const float* fc3w   = (const float*)d_in[37];
    const float* fc3b   = (const float*)d_in[38];
    float* out = (float*)d_out;

    hipLaunchKernelGGL(net_kernel, dim3(4096), dim3(256), 0, stream,
        x, ln_g, ln_b, Wup_l, bup_l, Wup_r, bup_r, conv_w, conv_b,
        Wq, bq, Wk, bk, Wv, bv, Wif, bif, gn_g, gn_b, skip, Wdown, bdown,
        s_ln_g, s_ln_b, sW, sR, sb, s_gn_g, s_gn_b,
        sWup1, sbup1, sWup2, sbup2, sWdown, sbdown,
        fc1w, fc1b, fc3w, fc3b, out);
}

// Round 16
// 104.509 us; speedup vs baseline: 1.6094x; 1.6094x over previous
//
#include <hip/hip_runtime.h>
#include <hip/hip_bf16.h>

#define SS 30
#define DD 14
#define MM 28

// Per-batch LDS float offsets (PB = 1844 fl = 7,376 B; block = 4 batches = 29,504 B)
#define HX  0     // 435: xn fp32(420) [A..urv] -> h bf16 stride29 (870us) [MFMA..G] -> y_m fp32(420) [H..L]
#define CQ  436   // 640: c bf16 32x40us [B..MFMA,G] -> yn fp32(420) [I..J] -> tanh(y_s)(420) [L..M]
#define UE  1076  // 640: ul bf16 [B..MFMA] -> e bf16 [G..H] -> gx(240) [J..K] -> UV(90) [L0..L]
#define ST2 1716  // 64: gif [..D3] -> G0 stats stride2 [G0..G] -> hs(60) [K..L0]
#define EA  1780  // 32: exp(a_s), pads 30,31 = 0
#define ECM 1812  // 32: exp(-cm_t), pads = 0 -> inv (G0)
#define PB  1844

#define WSYNC() asm volatile("" ::: "memory")

typedef short bshort8 __attribute__((ext_vector_type(8)));
typedef float f32x16 __attribute__((ext_vector_type(16)));

union __align__(16) FragU { unsigned int u[4]; bshort8 v; };

__device__ __forceinline__ float frcp(float v){ return __builtin_amdgcn_rcpf(v); }
__device__ __forceinline__ float frsq(float v){ return __builtin_amdgcn_rsqf(v); }
__device__ __forceinline__ float fsigm(float v){ return frcp(1.f+__expf(-v)); }
__device__ __forceinline__ float fsilu(float v){ return v*frcp(1.f+__expf(-v)); }
__device__ __forceinline__ float ftanh_(float v){
    float c = fminf(fmaxf(v, -15.f), 15.f);
    float e = __expf(2.f*c);
    return (e-1.f)*frcp(e+1.f);
}
__device__ __forceinline__ float fgelu(float v){
    float t = ftanh_(0.7978845608028654f*(v + 0.044715f*v*v*v));
    return 0.5f*v*(1.f+t);
}
__device__ __forceinline__ unsigned int pkbf(float a, float b){
    __hip_bfloat162 h = __float22bfloat162_rn(make_float2(a,b));
    return *reinterpret_cast<unsigned int*>(&h);
}
__device__ __forceinline__ unsigned short bfr(float f){
    __hip_bfloat16 h = __float2bfloat16(f);
    return *reinterpret_cast<unsigned short*>(&h);
}
__device__ __forceinline__ float lobf(unsigned int u){ return __uint_as_float(u<<16); }
__device__ __forceinline__ float hibf(unsigned int u){ return __uint_as_float(u & 0xFFFF0000u); }

__device__ __forceinline__ void load_wfrag(const float* __restrict__ W,
                                           const float* __restrict__ bias, float scale,
                                           int ncol, int lo, int hi, FragU& o0, FragU& o1){
    float t[16];
    #pragma unroll
    for (int sl=0; sl<2; sl++){
        #pragma unroll
        for (int r=0;r<8;r++){
            int h = 8*hi + r + 16*sl;
            float v = 0.f;
            if (lo < ncol){
                if (h < MM) v = W[h*ncol+lo]*scale;
                else if (h == MM) v = bias[lo]*scale;
            }
            t[sl*8+r] = v;
        }
    }
    #pragma unroll
    for (int p=0;p<4;p++){
        o0.u[p] = pkbf(t[2*p],   t[2*p+1]);
        o1.u[p] = pkbf(t[8+2*p], t[8+2*p+1]);
    }
}

__device__ __forceinline__ void asm_frag(const f32x16& d, int hi, FragU& s0, FragU& s1){
    unsigned int P[8], X[8];
    #pragma unroll
    for (int m=0;m<8;m++) P[m] = pkbf(d[2*m], d[2*m+1]);
    #pragma unroll
    for (int m=0;m<8;m++) X[m] = (unsigned int)__shfl_xor((int)P[m], 32, 64);
    s0.u[0] = hi ? X[2] : P[0];  s0.u[1] = hi ? X[3] : P[1];
    s0.u[2] = hi ? P[2] : X[0];  s0.u[3] = hi ? P[3] : X[1];
    s1.u[0] = hi ? X[6] : P[4];  s1.u[1] = hi ? X[7] : P[5];
    s1.u[2] = hi ? P[6] : X[4];  s1.u[3] = hi ? P[7] : X[5];
}

extern "C" __global__ void __launch_bounds__(256, 5)
net_kernel(const float* __restrict__ xg,
           const float* __restrict__ ln_g, const float* __restrict__ ln_b,
           const float* __restrict__ Wup_l, const float* __restrict__ bup_l,
           const float* __restrict__ Wup_r, const float* __restrict__ bup_r,
           const float* __restrict__ conv_w, const float* __restrict__ conv_b,
           const float* __restrict__ Wq, const float* __restrict__ bq,
           const float* __restrict__ Wk, const float* __restrict__ bk,
           const float* __restrict__ Wv, const float* __restrict__ bv,
           const float* __restrict__ Wif, const float* __restrict__ bif,
           const float* __restrict__ gn_g, const float* __restrict__ gn_b,
           const float* __restrict__ skip,
           const float* __restrict__ Wdown, const float* __restrict__ bdown,
           const float* __restrict__ s_ln_g, const float* __restrict__ s_ln_b,
           const float* __restrict__ sW, const float* __restrict__ sR, const float* __restrict__ sb,
           const float* __restrict__ s_gn_g, const float* __restrict__ s_gn_b,
           const float* __restrict__ sWup1, const float* __restrict__ sbup1,
           const float* __restrict__ sWup2, const float* __restrict__ sbup2,
           const float* __restrict__ sWdown, const float* __restrict__ sbdown,
           const float* __restrict__ fc1w, const float* __restrict__ fc1b,
           const float* __restrict__ fc3w, const float* __restrict__ fc3b,
           float* __restrict__ out)
{
    __shared__ __align__(16) float smAll[4*PB];
    const int tid  = threadIdx.x;
    const int wid  = tid >> 6;
    const int lane = tid & 63;
    const int b = blockIdx.x*4 + wid;
    float* sm = smAll + wid*PB;
    unsigned short* smu = reinterpret_cast<unsigned short*>(sm);
    char* smc = reinterpret_cast<char*>(sm);
    const float* xp = xg + (size_t)b * (SS*DD);

    const int lo = lane & 31, hi = lane >> 5;
    const int jq = lane % MM;
    const int gq = lane / MM;
    const bool act = lane < 56;
    const int jqi = act ? jq : 0;

    // ---- bf16 staging pads: cols 28..31 = (1,0,0,0); rows 30,31 = 0 ----
    if (lane < SS){
        *(uint2*)(smc + CQ*4 + lane*80 + 56) = make_uint2(0x3F80u, 0u);
        *(uint2*)(smc + UE*4 + lane*80 + 56) = make_uint2(0x3F80u, 0u);
    }
    if (lane < 20){
        *(uint2*)(smc + CQ*4 + 30*80 + lane*8) = make_uint2(0u,0u);
        *(uint2*)(smc + UE*4 + 30*80 + lane*8) = make_uint2(0u,0u);
    }

    // ---- VALU weight preloads (B/C only) ----
    float wl[DD], cw[4];
    float blr, cbr;
    {
        #pragma unroll
        for (int d=0; d<DD; d++) wl[d] = Wup_l[d*MM+jqi];
        #pragma unroll
        for (int k=0; k<4; k++) cw[k] = conv_w[k*MM+jqi];
        blr = bup_l[jqi]; cbr = conv_b[jqi];
    }

    // ---- Phase A: LN1 -> xn (HX fp32) ----
    if (lane < SS){
        float xv[DD];
        const float2* xr = (const float2*)(xp + lane*DD);
        float s=0.f, s2=0.f;
        #pragma unroll
        for (int u=0;u<7;u++){ float2 f=xr[u]; xv[2*u]=f.x; xv[2*u+1]=f.y; s+=f.x+f.y; s2+=f.x*f.x+f.y*f.y; }
        float mu=s*(1.f/DD), var=s2*(1.f/DD)-mu*mu, rsg=frsq(var+1e-5f);
        #pragma unroll
        for (int d=0; d<DD; d++) sm[HX+lane*DD+d] = (xv[d]-mu)*rsg*ln_g[d]+ln_b[d];
    }
    WSYNC();

    // ---- Phase B+C fused: ul in regs -> ul bf16 (UE) + conv/silu -> c bf16 (CQ) ----
    {
        float ulr[15];
        #pragma unroll
        for (int tt=0; tt<15; tt++){
            int t = gq*15+tt;
            float a = blr;
            if (act){
                const float2* xr = (const float2*)&sm[HX + t*DD];
                #pragma unroll
                for (int u=0;u<7;u++){ float2 f = xr[u]; a += f.x*wl[2*u] + f.y*wl[2*u+1]; }
                smu[UE*2 + t*40 + jq] = bfr(a);
            }
            ulr[tt] = a;
        }
        float u12 = __shfl(ulr[12], jq, 64);
        float u13 = __shfl(ulr[13], jq, 64);
        float u14 = __shfl(ulr[14], jq, 64);
        float gqf = (gq==1) ? 1.f : 0.f;
        #pragma unroll
        for (int tt=0; tt<15; tt++){
            int t = gq*15+tt;
            float h3, h2, h1;
            if (tt>=3){ h3=ulr[tt-3]; h2=ulr[tt-2]; h1=ulr[tt-1]; }
            else if (tt==2){ h3=gqf*u14; h2=ulr[0]; h1=ulr[1]; }
            else if (tt==1){ h3=gqf*u13; h2=gqf*u14; h1=ulr[0]; }
            else           { h3=gqf*u12; h2=gqf*u13; h1=gqf*u14; }
            float a = cbr + cw[0]*h3 + cw[1]*h2 + cw[2]*h1 + cw[3]*ulr[tt];
            if (act) smu[CQ*2 + t*40 + jq] = bfr(fsilu(a));
        }
    }
    WSYNC();

    // ---- gif = c(bf16) @ Wif + bif -> ST2 ----
    if (lane < SS*2){
        int t=lane>>1, gg=lane&1;
        float a = bif[gg];
        const uint2* cr = (const uint2*)(smc + CQ*4 + t*80);
        #pragma unroll
        for (int p=0;p<7;p++){
            uint2 cu = cr[p];
            a += lobf(cu.x)*Wif[(4*p)*2+gg]   + hibf(cu.x)*Wif[(4*p+1)*2+gg]
               + lobf(cu.y)*Wif[(4*p+2)*2+gg] + hibf(cu.y)*Wif[(4*p+3)*2+gg];
        }
        sm[ST2+lane]=a;
    }
    WSYNC();

    // ---- D3: gate pre-scan -> EA, ECM (pads 30,31 = 0) ----
    if (lane < SS){
        float i_ = sm[ST2+2*lane], f_ = sm[ST2+2*lane+1];
        float F = f_, v;
        v = __shfl_up(F,1,64);  if (lane>=1)  F += v;
        v = __shfl_up(F,2,64);  if (lane>=2)  F += v;
        v = __shfl_up(F,4,64);  if (lane>=4)  F += v;
        v = __shfl_up(F,8,64);  if (lane>=8)  F += v;
        v = __shfl_up(F,16,64); if (lane>=16) F += v;
        float a = i_ - F;
        float cm = a;
        v = __shfl_up(cm,1,64);  if (lane>=1)  cm = fmaxf(cm,v);
        v = __shfl_up(cm,2,64);  if (lane>=2)  cm = fmaxf(cm,v);
        v = __shfl_up(cm,4,64);  if (lane>=4)  cm = fmaxf(cm,v);
        v = __shfl_up(cm,8,64);  if (lane>=8)  cm = fmaxf(cm,v);
        v = __shfl_up(cm,16,64); if (lane>=16) cm = fmaxf(cm,v);
        cm = fmaxf(cm, 0.f);
        sm[EA+lane]  = __expf(a);
        sm[ECM+lane] = __expf(-cm);
    } else if (lane < 32){
        sm[EA+lane] = 0.f; sm[ECM+lane] = 0.f;
    }
    WSYNC();

    // ---- silu(ur) precompute, packed bf16 (8 regs; last xn consumer) ----
    unsigned int urp[8];
    {
        float wr[DD], brr = bup_r[jqi];
        #pragma unroll
        for (int d=0;d<DD;d++) wr[d]=Wup_r[d*MM+jqi];
        float slv[15];
        #pragma unroll
        for (int tt=0; tt<15; tt++){
            int t = gq*15+tt;
            float a = brr;
            if (act){
                const float2* xr = (const float2*)&sm[HX + t*DD];
                #pragma unroll
                for (int u=0;u<7;u++){ float2 f=xr[u]; a += f.x*wr[2*u]+f.y*wr[2*u+1]; }
            }
            slv[tt] = fsilu(a);
        }
        #pragma unroll
        for (int p=0;p<7;p++) urp[p] = pkbf(slv[2*p], slv[2*p+1]);
        urp[7] = pkbf(slv[14], 0.f);
    }
    WSYNC();

    // ================= MFMA section: sequenced accumulators =================
    {
        FragU cf0 = *(const FragU*)(smc + CQ*4 + lo*80 + hi*16);
        FragU cf1 = *(const FragU*)(smc + CQ*4 + lo*80 + hi*16 + 32);

        FragU eq0, eq1, ek0, ek1;
        {
            FragU wq0, wq1;
            load_wfrag(Wq, bq, 1.f, MM, lo, hi, wq0, wq1);
            f32x16 aq = {};
            aq = __builtin_amdgcn_mfma_f32_32x32x16_bf16(wq0.v, cf0.v, aq, 0,0,0);
            aq = __builtin_amdgcn_mfma_f32_32x32x16_bf16(wq1.v, cf1.v, aq, 0,0,0);
            asm_frag(aq, hi, eq0, eq1);
        }
        {
            const float rs28 = 0.18898223650461363f;
            FragU wk0, wk1;
            load_wfrag(Wk, bk, rs28, MM, lo, hi, wk0, wk1);
            f32x16 ak = {};
            ak = __builtin_amdgcn_mfma_f32_32x32x16_bf16(wk0.v, cf0.v, ak, 0,0,0);
            ak = __builtin_amdgcn_mfma_f32_32x32x16_bf16(wk1.v, cf1.v, ak, 0,0,0);
            asm_frag(ak, hi, ek0, ek1);
        }
        FragU fa0, fa1;
        {
            f32x16 es = {};
            es = __builtin_amdgcn_mfma_f32_32x32x16_bf16(ek0.v, eq0.v, es, 0,0,0);
            es = __builtin_amdgcn_mfma_f32_32x32x16_bf16(ek1.v, eq1.v, es, 0,0,0);
            float ecmt = sm[ECM + lo];
            #pragma unroll
            for (int g=0; g<16; g++){
                int srow = (g&3) + 8*(g>>2) + 4*hi;
                float w = sm[EA + srow] * ecmt;
                es[g] = (srow <= lo) ? es[g]*w : 0.f;
            }
            asm_frag(es, hi, fa0, fa1);
        }
        FragU vb0, vb1;
        {
            FragU wv0, wv1;
            load_wfrag(Wv, bv, 1.f, MM, lo, hi, wv0, wv1);
            FragU uf0 = *(const FragU*)(smc + UE*4 + lo*80 + hi*16);
            FragU uf1 = *(const FragU*)(smc + UE*4 + lo*80 + hi*16 + 32);
            f32x16 av = {};
            av = __builtin_amdgcn_mfma_f32_32x32x16_bf16(uf0.v, wv0.v, av, 0,0,0);
            av = __builtin_amdgcn_mfma_f32_32x32x16_bf16(uf1.v, wv1.v, av, 0,0,0);
            asm_frag(av, hi, vb0, vb1);
        }
        if (lo == MM){
            const unsigned int ONE2 = 0x3F803F80u;
            vb0.u[0]=ONE2; vb0.u[1]=ONE2; vb0.u[2]=ONE2; vb0.u[3]=ONE2;
            vb1.u[0]=ONE2; vb1.u[1]=ONE2; vb1.u[2]=ONE2; vb1.u[3]= hi ? 0u : ONE2;
        }
        f32x16 hacc = {};
        hacc = __builtin_amdgcn_mfma_f32_32x32x16_bf16(fa0.v, vb0.v, hacc, 0,0,0);
        hacc = __builtin_amdgcn_mfma_f32_32x32x16_bf16(fa1.v, vb1.v, hacc, 0,0,0);

        // h -> HX bf16 stride29 (xn dead); trow<30, lo<29
        #pragma unroll
        for (int g=0; g<16; g++){
            int trow = (g&3) + 8*(g>>2) + 4*hi;
            if (lo < 29 && trow < SS) smu[HX*2 + trow*29 + lo] = bfr(hacc[g]);
        }
    }
    WSYNC();

    // ---- VALU preloads for G/L ----
    const int dq  = lane % DD;
    const int g4  = lane / DD;
    const int dqi = act ? dq : 0;
    float skr=skip[jqi], ggr=gn_g[jqi], gbr=gn_b[jqi];
    float swd0 = sWdown[0*DD+dqi], swd1 = sWdown[1*DD+dqi], swd2 = sWdown[2*DD+dqi];
    float sbd  = sbdown[dqi];

    // ---- Phase G0: per-t stats (h bf16; rowsum at col 28) ----
    if (lane < SS){
        float s=0.f,s2=0.f;
        #pragma unroll
        for (int u=0;u<MM;u++){
            float v = lobf((unsigned int)smu[HX*2 + lane*29 + u]);
            s+=v; s2+=v*v;
        }
        float rsum = lobf((unsigned int)smu[HX*2 + lane*29 + MM]);
        float inv = frcp(fmaxf(fabsf(rsum), 1.f));
        float mu=s*(1.f/MM), var=s2*(1.f/MM)-mu*mu;
        sm[ST2+lane*2]   = mu*inv;
        sm[ST2+lane*2+1] = frsq(var*inv*inv + 1e-5f);
        sm[ECM+lane]     = inv;
    }
    WSYNC();

    // ---- Phase G: e = (hn + skip*c)*silu_ur -> e bf16 (UE) ----
    #pragma unroll
    for (int tt=0;tt<15;tt++){
        int t=gq*15+tt;
        if (act){
            float inv = sm[ECM+t];
            float hv = lobf((unsigned int)smu[HX*2 + t*29 + jq])*inv;
            float hn = (hv-sm[ST2+t*2])*sm[ST2+t*2+1]*ggr + gbr;
            float cv = lobf((unsigned int)smu[CQ*2 + t*40 + jq]);
            float h2 = hn + skr*cv;
            float slu = (tt&1) ? hibf(urp[tt>>1]) : lobf(urp[tt>>1]);
            smu[UE*2 + t*40 + jq] = bfr(h2 * slu);
        }
    }
    WSYNC();

    // ---- Phase H (MFMA): y_m = e @ WdownAug + x -> HX fp32 (h dead) ----
    {
        FragU wd0, wd1;
        load_wfrag(Wdown, bdown, 1.f, DD, lo, hi, wd0, wd1);
        FragU ef0 = *(const FragU*)(smc + UE*4 + lo*80 + hi*16);
        FragU ef1 = *(const FragU*)(smc + UE*4 + lo*80 + hi*16 + 32);
        f32x16 ym = {};
        ym = __builtin_amdgcn_mfma_f32_32x32x16_bf16(ef0.v, wd0.v, ym, 0,0,0);
        ym = __builtin_amdgcn_mfma_f32_32x32x16_bf16(ef1.v, wd1.v, ym, 0,0,0);
        #pragma unroll
        for (int g=0; g<16; g++){
            int trow = (g&3) + 8*(g>>2) + 4*hi;
            if (lo < DD && trow < SS) sm[HX + trow*DD + lo] = ym[g] + xp[trow*DD + lo];
        }
    }
    WSYNC();

    // ---- Phase I: sLSTM LN -> yn fp32 into CQ (c dead) ----
    if (lane < SS){
        const float2* yr=(const float2*)&sm[HX+lane*DD];
        float yv[DD];
        float s=0.f,s2=0.f;
        #pragma unroll
        for (int u=0;u<7;u++){ float2 f=yr[u]; yv[2*u]=f.x; yv[2*u+1]=f.y; s+=f.x+f.y; s2+=f.x*f.x+f.y*f.y; }
        float mu=s*(1.f/DD), var=s2*(1.f/DD)-mu*mu, rs=frsq(var+1e-5f);
        #pragma unroll
        for (int d=0;d<DD;d++)
            sm[CQ+lane*DD+d] = (yv[d]-mu)*rs*s_ln_g[d] + s_ln_b[d];
    }
    WSYNC();

    // ---- Phase J: gx = yn @ sW + sb -> UE (e dead) ----
    for (int idx=lane; idx<SS*8; idx+=64){
        int t=idx>>3, gg=idx&7;
        float a=sb[gg];
        const float2* yr = (const float2*)&sm[CQ+t*DD];
        #pragma unroll
        for (int u=0;u<7;u++){
            float2 f=yr[u];
            a += f.x*sW[(2*u)*8+gg] + f.y*sW[(2*u+1)*8+gg];
        }
        sm[UE+idx]=a;
    }
    WSYNC();

    // ---- Phase K: sLSTM scan (rolled; lane0 writes hs -> ST2) ----
    {
        float R0[8], R1[8];
        #pragma unroll
        for (int g=0; g<8; g++){ R0[g]=sR[g]; R1[g]=sR[8+g]; }
        float h0=0.f,h1=0.f,c0=0.f,c1=0.f,n0=0.f,n1=0.f,m0=0.f,m1=0.f;
        const float2* gr = (const float2*)&sm[UE];
        float2 A0=gr[0], A1=gr[1], A2=gr[2], A3=gr[3];
        #pragma unroll 1
        for (int t=0; t<SS; t++){
            float2 N0,N1,N2,N3;
            if (t < SS-1){
                const float2* nx = (const float2*)&sm[UE+(t+1)*8];
                N0=nx[0]; N1=nx[1]; N2=nx[2]; N3=nx[3];
            }
            float g0=A0.x+h0*R0[0]+h1*R1[0], g1=A0.y+h0*R0[1]+h1*R1[1];
            float g2=A1.x+h0*R0[2]+h1*R1[2], g3=A1.y+h0*R0[3]+h1*R1[3];
            float g4v=A2.x+h0*R0[4]+h1*R1[4], g5=A2.y+h0*R0[5]+h1*R1[5];
            float g6=A3.x+h0*R0[6]+h1*R1[6], g7=A3.y+h0*R0[7]+h1*R1[7];
            float z0=ftanh_(g0), z1=ftanh_(g1);
            float mn0=fmaxf(g4v+m0, g2), mn1=fmaxf(g5+m1, g3);
            float ie0=__expf(g2-mn0), ie1=__expf(g3-mn1);
            float fe0=__expf(g4v+m0-mn0), fe1=__expf(g5+m1-mn1);
            c0 = fe0*c0 + ie0*z0;  c1 = fe1*c1 + ie1*z1;
            n0 = fe0*n0 + ie0;     n1 = fe1*n1 + ie1;
            h0 = c0*frcp((1.f+__expf(-g6))*n0);
            h1 = c1*frcp((1.f+__expf(-g7))*n1);
            m0 = mn0; m1 = mn1;
            if (lane == 0){ sm[ST2+t*2] = h0; sm[ST2+t*2+1] = h1; }
            A0=N0; A1=N1; A2=N2; A3=N3;
        }
    }
    WSYNC();

    // ---- Phase L0: per-t u-values -> UE (gx dead) ----
    if (lane < SS){
        float a0 = sm[ST2+lane*2], a1 = sm[ST2+lane*2+1];
        float mu = 0.5f*(a0+a1);
        float d0 = a0-mu, d1 = a1-mu;
        float var = 0.5f*(d0*d0 + d1*d1);
        float rsg = frsq(var + 1e-5f);
        float hn0 = d0*rsg*s_gn_g[0] + s_gn_b[0];
        float hn1 = d1*rsg*s_gn_g[1] + s_gn_b[1];
        #pragma unroll
        for (int u3=0; u3<3; u3++){
            float p1 = hn0*sWup1[u3] + hn1*sWup1[3+u3] + sbup1[u3];
            float p2 = hn0*sWup2[u3] + hn1*sWup2[3+u3] + sbup2[u3];
            sm[UE + lane*3 + u3] = fgelu(p1)*p2;
        }
    }
    WSYNC();

    // ---- Phase L: y_s + tanh -> CQ (yn dead) ----
    #pragma unroll
    for (int tt=0; tt<8; tt++){
        int t=g4*8+tt;
        if (act && t<SS){
            float acc = sbd + sm[HX+t*DD+dq]
                      + sm[UE+t*3]*swd0 + sm[UE+t*3+1]*swd1 + sm[UE+t*3+2]*swd2;
            sm[CQ+t*DD+dq] = ftanh_(acc);
        }
    }
    WSYNC();

    // ---- Phase M: head fc1(420->32,relu) + fc3(32->1) ----
    {
        int j = lane & 31, half = lane >> 5;
        const float2* tyr = (const float2*)&sm[CQ + half*210];
        float a = 0.f;
        const float* w1 = fc1w + (half*210)*32 + j;
        #pragma unroll 1
        for (int d2=0; d2<105; d2++){
            float2 tv = tyr[d2];
            a += tv.x*w1[(2*d2)*32] + tv.y*w1[(2*d2+1)*32];
        }
        a += __shfl_xor(a, 32, 64);
        a += fc1b[j];
        float r = fmaxf(a, 0.f);
        float p = r * fc3w[j];
        #pragma unroll
        for (int off=16; off>=1; off>>=1) p += __shfl_xor(p, off, 64);
        if (lane == 0) out[b] = p + fc3b[0];
    }
}

extern "C" void kernel_launch(void* const* d_in, const int* in_sizes, int n_in,
                              void* d_out, int out_size, void* d_ws, size_t ws_size,
                              hipStream_t stream) {
    const float* x      = (const float*)d_in[0];
    const float* ln_g   = (const float*)d_in[1];
    const float* ln_b   = (const float*)d_in[2];
    const float* Wup_l  = (const float*)d_in[3];
    const float* bup_l  = (const float*)d_in[4];
    const float* Wup_r  = (const float*)d_in[5];
    const float* bup_r  = (const float*)d_in[6];
    const float* conv_w = (const float*)d_in[7];
    const float* conv_b = (const float*)d_in[8];
    const float* Wq     = (const float*)d_in[9];
    const float* bq     = (const float*)d_in[10];
    const float* Wk     = (const float*)d_in[11];
    const float* bk     = (const float*)d_in[12];
    const float* Wv     = (const float*)d_in[13];
    const float* bv     = (const float*)d_in[14];
    const float* Wif    = (const float*)d_in[15];
    const float* bif    = (const float*)d_in[16];
    const float* gn_g   = (const float*)d_in[17];
    const float* gn_b   = (const float*)d_in[18];
    const float* skip   = (const float*)d_in[19];
    const float* Wdown  = (const float*)d_in[20];
    const float* bdown  = (const float*)d_in[21];
    const float* s_ln_g = (const float*)d_in[22];
    const float* s_ln_b = (const float*)d_in[23];
    const float* sW     = (const float*)d_in[24];
    const float* sR     = (const float*)d_in[25];
    const float* sb     = (const float*)d_in[26];
    const float* s_gn_g = (const float*)d_in[27];
    const float* s_gn_b = (const float*)d_in[28];
    const float* sWup1  = (const float*)d_in[29];
    const float* sbup1  = (const float*)d_in[30];
    const float* sWup2  = (const float*)d_in[31];
    const float* sbup2  = (const float*)d_in[32];
    const float* sWdown = (const float*)d_in[33];
    const float* sbdown = (const float*)d_in[34];
    const float* fc1w   = (const float*)d_in[35];
    const float* fc1b   = (const float*)d_in[36];
    const float* fc3w   = (const float*)d_in[37];
    const float* fc3b   = (const float*)d_in[38];
    float* out = (float*)d_out;

    hipLaunchKernelGGL(net_kernel, dim3(2048), dim3(256), 0, stream,
        x, ln_g, ln_b, Wup_l, bup_l, Wup_r, bup_r, conv_w, conv_b,
        Wq, bq, Wk, bk, Wv, bv, Wif, bif, gn_g, gn_b, skip, Wdown, bdown,
        s_ln_g, s_ln_b, sW, sR, sb, s_gn_g, s_gn_b,
        sWup1, sbup1, sWup2, sbup2, sWdown, sbdown,
        fc1w, fc1b, fc3w, fc3b, out);
}

// Round 17
// 102.356 us; speedup vs baseline: 1.6432x; 1.0210x over previous
//
#include <hip/hip_runtime.h>
#include <hip/hip_bf16.h>

#define SS 30
#define DD 14
#define MM 28

// Per-batch LDS float offsets (PB = 1844 fl = 7,376 B; block = 4 batches = 29,504 B)
#define HX  0     // 435: xn fp32(420) [A..urv] -> h bf16 stride29 (870us) [MFMA..G] -> y_m fp32(420) [H..L]
#define CQ  436   // 640: c bf16 32x40us [B..MFMA,G] -> yn fp32(420) [I..J] -> tanh(y_s)(420) [L..M]
#define UE  1076  // 640: ul bf16 [B..MFMA] -> e bf16 [G..H] -> gx(240) [J..K] -> UV(90) [L0..L]
#define ST2 1716  // 64: gif [..D3] -> G0 stats stride2 [G0..G] -> hs(60) [K..L0]
#define EA  1780  // 32: exp(a_s), pads 30,31 = 0
#define ECM 1812  // 32: exp(-cm_t), pads = 0 -> inv (G0)
#define PB  1844

#define WSYNC() asm volatile("" ::: "memory")

typedef short bshort8 __attribute__((ext_vector_type(8)));
typedef float f32x16 __attribute__((ext_vector_type(16)));

union __align__(16) FragU { unsigned int u[4]; bshort8 v; };

__device__ __forceinline__ float frcp(float v){ return __builtin_amdgcn_rcpf(v); }
__device__ __forceinline__ float frsq(float v){ return __builtin_amdgcn_rsqf(v); }
__device__ __forceinline__ float fsigm(float v){ return frcp(1.f+__expf(-v)); }
__device__ __forceinline__ float fsilu(float v){ return v*frcp(1.f+__expf(-v)); }
__device__ __forceinline__ float ftanh_(float v){
    float c = fminf(fmaxf(v, -15.f), 15.f);
    float e = __expf(2.f*c);
    return (e-1.f)*frcp(e+1.f);
}
__device__ __forceinline__ float fgelu(float v){
    float t = ftanh_(0.7978845608028654f*(v + 0.044715f*v*v*v));
    return 0.5f*v*(1.f+t);
}
__device__ __forceinline__ unsigned int pkbf(float a, float b){
    __hip_bfloat162 h = __float22bfloat162_rn(make_float2(a,b));
    return *reinterpret_cast<unsigned int*>(&h);
}
__device__ __forceinline__ unsigned short bfr(float f){
    __hip_bfloat16 h = __float2bfloat16(f);
    return *reinterpret_cast<unsigned short*>(&h);
}
__device__ __forceinline__ float lobf(unsigned int u){ return __uint_as_float(u<<16); }
__device__ __forceinline__ float hibf(unsigned int u){ return __uint_as_float(u & 0xFFFF0000u); }

__device__ __forceinline__ void load_wfrag(const float* __restrict__ W,
                                           const float* __restrict__ bias, float scale,
                                           int ncol, int lo, int hi, FragU& o0, FragU& o1){
    float t[16];
    #pragma unroll
    for (int sl=0; sl<2; sl++){
        #pragma unroll
        for (int r=0;r<8;r++){
            int h = 8*hi + r + 16*sl;
            float v = 0.f;
            if (lo < ncol){
                if (h < MM) v = W[h*ncol+lo]*scale;
                else if (h == MM) v = bias[lo]*scale;
            }
            t[sl*8+r] = v;
        }
    }
    #pragma unroll
    for (int p=0;p<4;p++){
        o0.u[p] = pkbf(t[2*p],   t[2*p+1]);
        o1.u[p] = pkbf(t[8+2*p], t[8+2*p+1]);
    }
}

__device__ __forceinline__ void asm_frag(const f32x16& d, int hi, FragU& s0, FragU& s1){
    unsigned int P[8], X[8];
    #pragma unroll
    for (int m=0;m<8;m++) P[m] = pkbf(d[2*m], d[2*m+1]);
    #pragma unroll
    for (int m=0;m<8;m++) X[m] = (unsigned int)__shfl_xor((int)P[m], 32, 64);
    s0.u[0] = hi ? X[2] : P[0];  s0.u[1] = hi ? X[3] : P[1];
    s0.u[2] = hi ? P[2] : X[0];  s0.u[3] = hi ? P[3] : X[1];
    s1.u[0] = hi ? X[6] : P[4];  s1.u[1] = hi ? X[7] : P[5];
    s1.u[2] = hi ? P[6] : X[4];  s1.u[3] = hi ? P[7] : X[5];
}

extern "C" __global__ void __launch_bounds__(256, 5)
net_kernel(const float* __restrict__ xg,
           const float* __restrict__ ln_g, const float* __restrict__ ln_b,
           const float* __restrict__ Wup_l, const float* __restrict__ bup_l,
           const float* __restrict__ Wup_r, const float* __restrict__ bup_r,
           const float* __restrict__ conv_w, const float* __restrict__ conv_b,
           const float* __restrict__ Wq, const float* __restrict__ bq,
           const float* __restrict__ Wk, const float* __restrict__ bk,
           const float* __restrict__ Wv, const float* __restrict__ bv,
           const float* __restrict__ Wif, const float* __restrict__ bif,
           const float* __restrict__ gn_g, const float* __restrict__ gn_b,
           const float* __restrict__ skip,
           const float* __restrict__ Wdown, const float* __restrict__ bdown,
           const float* __restrict__ s_ln_g, const float* __restrict__ s_ln_b,
           const float* __restrict__ sW, const float* __restrict__ sR, const float* __restrict__ sb,
           const float* __restrict__ s_gn_g, const float* __restrict__ s_gn_b,
           const float* __restrict__ sWup1, const float* __restrict__ sbup1,
           const float* __restrict__ sWup2, const float* __restrict__ sbup2,
           const float* __restrict__ sWdown, const float* __restrict__ sbdown,
           const float* __restrict__ fc1w, const float* __restrict__ fc1b,
           const float* __restrict__ fc3w, const float* __restrict__ fc3b,
           float* __restrict__ out)
{
    __shared__ __align__(16) float smAll[4*PB];
    const int tid  = threadIdx.x;
    const int wid  = tid >> 6;
    const int lane = tid & 63;
    const int b = blockIdx.x*4 + wid;
    float* sm = smAll + wid*PB;
    unsigned short* smu = reinterpret_cast<unsigned short*>(sm);
    char* smc = reinterpret_cast<char*>(sm);
    const float* xp = xg + (size_t)b * (SS*DD);

    const int lo = lane & 31, hi = lane >> 5;
    const int jq = lane % MM;
    const int gq = lane / MM;
    const bool act = lane < 56;
    const int jqi = act ? jq : 0;

    // ---- bf16 staging pads: cols 28..31 = (1,0,0,0); rows 30,31 = 0 ----
    if (lane < SS){
        *(uint2*)(smc + CQ*4 + lane*80 + 56) = make_uint2(0x3F80u, 0u);
        *(uint2*)(smc + UE*4 + lane*80 + 56) = make_uint2(0x3F80u, 0u);
    }
    if (lane < 20){
        *(uint2*)(smc + CQ*4 + 30*80 + lane*8) = make_uint2(0u,0u);
        *(uint2*)(smc + UE*4 + 30*80 + lane*8) = make_uint2(0u,0u);
    }

    // ---- Phase A: LN1 -> xn (HX fp32) ----
    if (lane < SS){
        float xv[DD];
        const float2* xr = (const float2*)(xp + lane*DD);
        float s=0.f, s2=0.f;
        #pragma unroll
        for (int u=0;u<7;u++){ float2 f=xr[u]; xv[2*u]=f.x; xv[2*u+1]=f.y; s+=f.x+f.y; s2+=f.x*f.x+f.y*f.y; }
        float mu=s*(1.f/DD), var=s2*(1.f/DD)-mu*mu, rsg=frsq(var+1e-5f);
        #pragma unroll
        for (int d=0; d<DD; d++) sm[HX+lane*DD+d] = (xv[d]-mu)*rsg*ln_g[d]+ln_b[d];
    }
    WSYNC();

    // ---- Phase B+C fused: ul in regs -> ul bf16 (UE) + conv/silu -> c bf16 (CQ) ----
    {
        float wl[DD], cw[4];
        float blr = bup_l[jqi], cbr = conv_b[jqi];
        #pragma unroll
        for (int d=0; d<DD; d++) wl[d] = Wup_l[d*MM+jqi];
        #pragma unroll
        for (int k=0; k<4; k++) cw[k] = conv_w[k*MM+jqi];

        float ulr[15];
        #pragma unroll
        for (int tt=0; tt<15; tt++){
            int t = gq*15+tt;
            float a = blr;
            if (act){
                const float2* xr = (const float2*)&sm[HX + t*DD];
                #pragma unroll
                for (int u=0;u<7;u++){ float2 f = xr[u]; a += f.x*wl[2*u] + f.y*wl[2*u+1]; }
                smu[UE*2 + t*40 + jq] = bfr(a);
            }
            ulr[tt] = a;
        }
        float u12 = __shfl(ulr[12], jq, 64);
        float u13 = __shfl(ulr[13], jq, 64);
        float u14 = __shfl(ulr[14], jq, 64);
        float gqf = (gq==1) ? 1.f : 0.f;
        #pragma unroll
        for (int tt=0; tt<15; tt++){
            int t = gq*15+tt;
            float h3, h2, h1;
            if (tt>=3){ h3=ulr[tt-3]; h2=ulr[tt-2]; h1=ulr[tt-1]; }
            else if (tt==2){ h3=gqf*u14; h2=ulr[0]; h1=ulr[1]; }
            else if (tt==1){ h3=gqf*u13; h2=gqf*u14; h1=ulr[0]; }
            else           { h3=gqf*u12; h2=gqf*u13; h1=gqf*u14; }
            float a = cbr + cw[0]*h3 + cw[1]*h2 + cw[2]*h1 + cw[3]*ulr[tt];
            if (act) smu[CQ*2 + t*40 + jq] = bfr(fsilu(a));
        }
    }
    WSYNC();

    // ---- gif = c(bf16) @ Wif + bif -> ST2 ----
    if (lane < SS*2){
        int t=lane>>1, gg=lane&1;
        float a = bif[gg];
        const uint2* cr = (const uint2*)(smc + CQ*4 + t*80);
        #pragma unroll
        for (int p=0;p<7;p++){
            uint2 cu = cr[p];
            a += lobf(cu.x)*Wif[(4*p)*2+gg]   + hibf(cu.x)*Wif[(4*p+1)*2+gg]
               + lobf(cu.y)*Wif[(4*p+2)*2+gg] + hibf(cu.y)*Wif[(4*p+3)*2+gg];
        }
        sm[ST2+lane]=a;
    }
    WSYNC();

    // ---- D3: gate pre-scan -> EA, ECM (pads 30,31 = 0) ----
    if (lane < SS){
        float i_ = sm[ST2+2*lane], f_ = sm[ST2+2*lane+1];
        float F = f_, v;
        v = __shfl_up(F,1,64);  if (lane>=1)  F += v;
        v = __shfl_up(F,2,64);  if (lane>=2)  F += v;
        v = __shfl_up(F,4,64);  if (lane>=4)  F += v;
        v = __shfl_up(F,8,64);  if (lane>=8)  F += v;
        v = __shfl_up(F,16,64); if (lane>=16) F += v;
        float a = i_ - F;
        float cm = a;
        v = __shfl_up(cm,1,64);  if (lane>=1)  cm = fmaxf(cm,v);
        v = __shfl_up(cm,2,64);  if (lane>=2)  cm = fmaxf(cm,v);
        v = __shfl_up(cm,4,64);  if (lane>=4)  cm = fmaxf(cm,v);
        v = __shfl_up(cm,8,64);  if (lane>=8)  cm = fmaxf(cm,v);
        v = __shfl_up(cm,16,64); if (lane>=16) cm = fmaxf(cm,v);
        cm = fmaxf(cm, 0.f);
        sm[EA+lane]  = __expf(a);
        sm[ECM+lane] = __expf(-cm);
    } else if (lane < 32){
        sm[EA+lane] = 0.f; sm[ECM+lane] = 0.f;
    }
    WSYNC();

    // ---- silu(ur) precompute, pairwise pack (2 live fp32; 8 packed regs) ----
    unsigned int urp[8];
    {
        float wr[DD], brr = bup_r[jqi];
        #pragma unroll
        for (int d=0;d<DD;d++) wr[d]=Wup_r[d*MM+jqi];
        #pragma unroll
        for (int p=0; p<8; p++){
            float a0 = brr, a1 = brr;
            if (act){
                int t = gq*15 + 2*p;
                const float2* xr = (const float2*)&sm[HX + t*DD];
                #pragma unroll
                for (int u=0;u<7;u++){ float2 f=xr[u]; a0 += f.x*wr[2*u]+f.y*wr[2*u+1]; }
                if (p < 7){
                    const float2* xr2 = (const float2*)&sm[HX + (t+1)*DD];
                    #pragma unroll
                    for (int u=0;u<7;u++){ float2 f=xr2[u]; a1 += f.x*wr[2*u]+f.y*wr[2*u+1]; }
                }
            }
            urp[p] = pkbf(fsilu(a0), fsilu(a1));
        }
    }
    WSYNC();

    // ================= MFMA section: sequenced accumulators =================
    {
        FragU cf0 = *(const FragU*)(smc + CQ*4 + lo*80 + hi*16);
        FragU cf1 = *(const FragU*)(smc + CQ*4 + lo*80 + hi*16 + 32);

        FragU eq0, eq1, ek0, ek1;
        {
            FragU wq0, wq1;
            load_wfrag(Wq, bq, 1.f, MM, lo, hi, wq0, wq1);
            f32x16 aq = {};
            aq = __builtin_amdgcn_mfma_f32_32x32x16_bf16(wq0.v, cf0.v, aq, 0,0,0);
            aq = __builtin_amdgcn_mfma_f32_32x32x16_bf16(wq1.v, cf1.v, aq, 0,0,0);
            asm_frag(aq, hi, eq0, eq1);
        }
        {
            const float rs28 = 0.18898223650461363f;
            FragU wk0, wk1;
            load_wfrag(Wk, bk, rs28, MM, lo, hi, wk0, wk1);
            f32x16 ak = {};
            ak = __builtin_amdgcn_mfma_f32_32x32x16_bf16(wk0.v, cf0.v, ak, 0,0,0);
            ak = __builtin_amdgcn_mfma_f32_32x32x16_bf16(wk1.v, cf1.v, ak, 0,0,0);
            asm_frag(ak, hi, ek0, ek1);
        }
        FragU fa0, fa1;
        {
            f32x16 es = {};
            es = __builtin_amdgcn_mfma_f32_32x32x16_bf16(ek0.v, eq0.v, es, 0,0,0);
            es = __builtin_amdgcn_mfma_f32_32x32x16_bf16(ek1.v, eq1.v, es, 0,0,0);
            float ecmt = sm[ECM + lo];
            #pragma unroll
            for (int g=0; g<16; g++){
                int srow = (g&3) + 8*(g>>2) + 4*hi;
                float w = sm[EA + srow] * ecmt;
                es[g] = (srow <= lo) ? es[g]*w : 0.f;
            }
            asm_frag(es, hi, fa0, fa1);
        }
        FragU vb0, vb1;
        {
            FragU wv0, wv1;
            load_wfrag(Wv, bv, 1.f, MM, lo, hi, wv0, wv1);
            FragU uf0 = *(const FragU*)(smc + UE*4 + lo*80 + hi*16);
            FragU uf1 = *(const FragU*)(smc + UE*4 + lo*80 + hi*16 + 32);
            f32x16 av = {};
            av = __builtin_amdgcn_mfma_f32_32x32x16_bf16(uf0.v, wv0.v, av, 0,0,0);
            av = __builtin_amdgcn_mfma_f32_32x32x16_bf16(uf1.v, wv1.v, av, 0,0,0);
            asm_frag(av, hi, vb0, vb1);
        }
        if (lo == MM){
            const unsigned int ONE2 = 0x3F803F80u;
            vb0.u[0]=ONE2; vb0.u[1]=ONE2; vb0.u[2]=ONE2; vb0.u[3]=ONE2;
            vb1.u[0]=ONE2; vb1.u[1]=ONE2; vb1.u[2]=ONE2; vb1.u[3]= hi ? 0u : ONE2;
        }
        f32x16 hacc = {};
        hacc = __builtin_amdgcn_mfma_f32_32x32x16_bf16(fa0.v, vb0.v, hacc, 0,0,0);
        hacc = __builtin_amdgcn_mfma_f32_32x32x16_bf16(fa1.v, vb1.v, hacc, 0,0,0);

        // h -> HX bf16 stride29 (xn dead); trow<30, lo<29
        #pragma unroll
        for (int g=0; g<16; g++){
            int trow = (g&3) + 8*(g>>2) + 4*hi;
            if (lo < 29 && trow < SS) smu[HX*2 + trow*29 + lo] = bfr(hacc[g]);
        }
    }
    WSYNC();

    // ---- VALU preloads for G/L ----
    const int dq  = lane % DD;
    const int g4  = lane / DD;
    const int dqi = act ? dq : 0;
    float skr=skip[jqi], ggr=gn_g[jqi], gbr=gn_b[jqi];
    float swd0 = sWdown[0*DD+dqi], swd1 = sWdown[1*DD+dqi], swd2 = sWdown[2*DD+dqi];
    float sbd  = sbdown[dqi];

    // ---- Phase G0: per-t stats (h bf16; rowsum at col 28) ----
    if (lane < SS){
        float s=0.f,s2=0.f;
        #pragma unroll
        for (int u=0;u<MM;u++){
            float v = lobf((unsigned int)smu[HX*2 + lane*29 + u]);
            s+=v; s2+=v*v;
        }
        float rsum = lobf((unsigned int)smu[HX*2 + lane*29 + MM]);
        float inv = frcp(fmaxf(fabsf(rsum), 1.f));
        float mu=s*(1.f/MM), var=s2*(1.f/MM)-mu*mu;
        sm[ST2+lane*2]   = mu*inv;
        sm[ST2+lane*2+1] = frsq(var*inv*inv + 1e-5f);
        sm[ECM+lane]     = inv;
    }
    WSYNC();

    // ---- Phase G: e = (hn + skip*c)*silu_ur -> e bf16 (UE) ----
    #pragma unroll
    for (int tt=0;tt<15;tt++){
        int t=gq*15+tt;
        if (act){
            float inv = sm[ECM+t];
            float hv = lobf((unsigned int)smu[HX*2 + t*29 + jq])*inv;
            float hn = (hv-sm[ST2+t*2])*sm[ST2+t*2+1]*ggr + gbr;
            float cv = lobf((unsigned int)smu[CQ*2 + t*40 + jq]);
            float h2 = hn + skr*cv;
            float slu = (tt&1) ? hibf(urp[tt>>1]) : lobf(urp[tt>>1]);
            smu[UE*2 + t*40 + jq] = bfr(h2 * slu);
        }
    }
    WSYNC();

    // ---- Phase H (MFMA): y_m = e @ WdownAug + x -> HX fp32 (h dead) ----
    {
        FragU wd0, wd1;
        load_wfrag(Wdown, bdown, 1.f, DD, lo, hi, wd0, wd1);
        FragU ef0 = *(const FragU*)(smc + UE*4 + lo*80 + hi*16);
        FragU ef1 = *(const FragU*)(smc + UE*4 + lo*80 + hi*16 + 32);
        f32x16 ym = {};
        ym = __builtin_amdgcn_mfma_f32_32x32x16_bf16(ef0.v, wd0.v, ym, 0,0,0);
        ym = __builtin_amdgcn_mfma_f32_32x32x16_bf16(ef1.v, wd1.v, ym, 0,0,0);
        #pragma unroll
        for (int g=0; g<16; g++){
            int trow = (g&3) + 8*(g>>2) + 4*hi;
            if (lo < DD && trow < SS) sm[HX + trow*DD + lo] = ym[g] + xp[trow*DD + lo];
        }
    }
    WSYNC();

    // ---- Phase I: sLSTM LN -> yn fp32 into CQ (c dead) ----
    if (lane < SS){
        const float2* yr=(const float2*)&sm[HX+lane*DD];
        float yv[DD];
        float s=0.f,s2=0.f;
        #pragma unroll
        for (int u=0;u<7;u++){ float2 f=yr[u]; yv[2*u]=f.x; yv[2*u+1]=f.y; s+=f.x+f.y; s2+=f.x*f.x+f.y*f.y; }
        float mu=s*(1.f/DD), var=s2*(1.f/DD)-mu*mu, rs=frsq(var+1e-5f);
        #pragma unroll
        for (int d=0;d<DD;d++)
            sm[CQ+lane*DD+d] = (yv[d]-mu)*rs*s_ln_g[d] + s_ln_b[d];
    }
    WSYNC();

    // ---- Phase J: gx = yn @ sW + sb -> UE (e dead) ----
    for (int idx=lane; idx<SS*8; idx+=64){
        int t=idx>>3, gg=idx&7;
        float a=sb[gg];
        const float2* yr = (const float2*)&sm[CQ+t*DD];
        #pragma unroll
        for (int u=0;u<7;u++){
            float2 f=yr[u];
            a += f.x*sW[(2*u)*8+gg] + f.y*sW[(2*u+1)*8+gg];
        }
        sm[UE+idx]=a;
    }
    WSYNC();

    // ---- Phase K: sLSTM scan (rolled; lane0 writes hs -> ST2) ----
    {
        float R0[8], R1[8];
        #pragma unroll
        for (int g=0; g<8; g++){ R0[g]=sR[g]; R1[g]=sR[8+g]; }
        float h0=0.f,h1=0.f,c0=0.f,c1=0.f,n0=0.f,n1=0.f,m0=0.f,m1=0.f;
        const float2* gr = (const float2*)&sm[UE];
        float2 A0=gr[0], A1=gr[1], A2=gr[2], A3=gr[3];
        #pragma unroll 1
        for (int t=0; t<SS; t++){
            float2 N0,N1,N2,N3;
            if (t < SS-1){
                const float2* nx = (const float2*)&sm[UE+(t+1)*8];
                N0=nx[0]; N1=nx[1]; N2=nx[2]; N3=nx[3];
            }
            float g0=A0.x+h0*R0[0]+h1*R1[0], g1=A0.y+h0*R0[1]+h1*R1[1];
            float g2=A1.x+h0*R0[2]+h1*R1[2], g3=A1.y+h0*R0[3]+h1*R1[3];
            float g4v=A2.x+h0*R0[4]+h1*R1[4], g5=A2.y+h0*R0[5]+h1*R1[5];
            float g6=A3.x+h0*R0[6]+h1*R1[6], g7=A3.y+h0*R0[7]+h1*R1[7];
            float z0=ftanh_(g0), z1=ftanh_(g1);
            float mn0=fmaxf(g4v+m0, g2), mn1=fmaxf(g5+m1, g3);
            float ie0=__expf(g2-mn0), ie1=__expf(g3-mn1);
            float fe0=__expf(g4v+m0-mn0), fe1=__expf(g5+m1-mn1);
            c0 = fe0*c0 + ie0*z0;  c1 = fe1*c1 + ie1*z1;
            n0 = fe0*n0 + ie0;     n1 = fe1*n1 + ie1;
            h0 = c0*frcp((1.f+__expf(-g6))*n0);
            h1 = c1*frcp((1.f+__expf(-g7))*n1);
            m0 = mn0; m1 = mn1;
            if (lane == 0){ sm[ST2+t*2] = h0; sm[ST2+t*2+1] = h1; }
            A0=N0; A1=N1; A2=N2; A3=N3;
        }
    }
    WSYNC();

    // ---- Phase L0: per-t u-values -> UE (gx dead) ----
    if (lane < SS){
        float a0 = sm[ST2+lane*2], a1 = sm[ST2+lane*2+1];
        float mu = 0.5f*(a0+a1);
        float d0 = a0-mu, d1 = a1-mu;
        float var = 0.5f*(d0*d0 + d1*d1);
        float rsg = frsq(var + 1e-5f);
        float hn0 = d0*rsg*s_gn_g[0] + s_gn_b[0];
        float hn1 = d1*rsg*s_gn_g[1] + s_gn_b[1];
        #pragma unroll
        for (int u3=0; u3<3; u3++){
            float p1 = hn0*sWup1[u3] + hn1*sWup1[3+u3] + sbup1[u3];
            float p2 = hn0*sWup2[u3] + hn1*sWup2[3+u3] + sbup2[u3];
            sm[UE + lane*3 + u3] = fgelu(p1)*p2;
        }
    }
    WSYNC();

    // ---- Phase L: y_s + tanh -> CQ (yn dead) ----
    #pragma unroll
    for (int tt=0; tt<8; tt++){
        int t=g4*8+tt;
        if (act && t<SS){
            float acc = sbd + sm[HX+t*DD+dq]
                      + sm[UE+t*3]*swd0 + sm[UE+t*3+1]*swd1 + sm[UE+t*3+2]*swd2;
            sm[CQ+t*DD+dq] = ftanh_(acc);
        }
    }
    WSYNC();

    // ---- Phase M: head fc1(420->32,relu) + fc3(32->1) ----
    {
        int j = lane & 31, half = lane >> 5;
        const float2* tyr = (const float2*)&sm[CQ + half*210];
        float a = 0.f;
        const float* w1 = fc1w + (half*210)*32 + j;
        #pragma unroll 1
        for (int d2=0; d2<105; d2++){
            float2 tv = tyr[d2];
            a += tv.x*w1[(2*d2)*32] + tv.y*w1[(2*d2+1)*32];
        }
        a += __shfl_xor(a, 32, 64);
        a += fc1b[j];
        float r = fmaxf(a, 0.f);
        float p = r * fc3w[j];
        #pragma unroll
        for (int off=16; off>=1; off>>=1) p += __shfl_xor(p, off, 64);
        if (lane == 0) out[b] = p + fc3b[0];
    }
}

extern "C" void kernel_launch(void* const* d_in, const int* in_sizes, int n_in,
                              void* d_out, int out_size, void* d_ws, size_t ws_size,
                              hipStream_t stream) {
    const float* x      = (const float*)d_in[0];
    const float* ln_g   = (const float*)d_in[1];
    const float* ln_b   = (const float*)d_in[2];
    const float* Wup_l  = (const float*)d_in[3];
    const float* bup_l  = (const float*)d_in[4];
    const float* Wup_r  = (const float*)d_in[5];
    const float* bup_r  = (const float*)d_in[6];
    const float* conv_w = (const float*)d_in[7];
    const float* conv_b = (const float*)d_in[8];
    const float* Wq     = (const float*)d_in[9];
    const float* bq     = (const float*)d_in[10];
    const float* Wk     = (const float*)d_in[11];
    const float* bk     = (const float*)d_in[12];
    const float* Wv     = (const float*)d_in[13];
    const float* bv     = (const float*)d_in[14];
    const float* Wif    = (const float*)d_in[15];
    const float* bif    = (const float*)d_in[16];
    const float* gn_g   = (const float*)d_in[17];
    const float* gn_b   = (const float*)d_in[18];
    const float* skip   = (const float*)d_in[19];
    const float* Wdown  = (const float*)d_in[20];
    const float* bdown  = (const float*)d_in[21];
    const float* s_ln_g = (const float*)d_in[22];
    const float* s_ln_b = (const float*)d_in[23];
    const float* sW     = (const float*)d_in[24];
    const float* sR     = (const float*)d_in[25];
    const float* sb     = (const float*)d_in[26];
    const float* s_gn_g = (const float*)d_in[27];
    const float* s_gn_b = (const float*)d_in[28];
    const float* sWup1  = (const float*)d_in[29];
    const float* sbup1  = (const float*)d_in[30];
    const float* sWup2  = (const float*)d_in[31];
    const float* sbup2  = (const float*)d_in[32];
    const float* sWdown = (const float*)d_in[33];
    const float* sbdown = (const float*)d_in[34];
    const float* fc1w   = (const float*)d_in[35];
    const float* fc1b   = (const float*)d_in[36];
    const float* fc3w   = (const float*)d_in[37];
    const float* fc3b   = (const float*)d_in[38];
    float* out = (float*)d_out;

    hipLaunchKernelGGL(net_kernel, dim3(2048), dim3(256), 0, stream,
        x, ln_g, ln_b, Wup_l, bup_l, Wup_r, bup_r, conv_w, conv_b,
        Wq, bq, Wk, bk, Wv, bv, Wif, bif, gn_g, gn_b, skip, Wdown, bdown,
        s_ln_g, s_ln_b, sW, sR, sb, s_gn_g, s_gn_b,
        sWup1, sbup1, sWup2, sbup2, sWdown, sbdown,
        fc1w, fc1b, fc3w, fc3b, out);
}

// Round 18
// 92.015 us; speedup vs baseline: 1.8279x; 1.1124x over previous
//
#include <hip/hip_runtime.h>
#include <hip/hip_bf16.h>

#define SS 30
#define DD 14
#define MM 28

// Per-batch LDS float offsets (PB = 1844 fl = 7,376 B; block = 4 batches = 29,504 B)
#define HX  0     // 435: xn fp32(420) [A..urv] -> h bf16 stride29 (870us) [MFMA..G] -> y_m fp32(420) [H..L]
#define CQ  436   // 640: c bf16 32x40us [B..MFMA,G] -> yn fp32(420) [I..J] -> tanh(y_s)(420) [L..M]
#define UE  1076  // 640: ul bf16 [B..MFMA] -> e bf16 [G..H] -> gx(240) [J..K] -> UV(90) [L0..L]
#define ST2 1716  // 64: gif [..D3] -> G0 stats stride2 [G0..G] -> hs(60) [K..L0]
#define EA  1780  // 32: exp(a_s), pads 30,31 = 0
#define ECM 1812  // 32: exp(-cm_t), pads = 0 -> inv (G0)
#define PB  1844

#define WSYNC() asm volatile("" ::: "memory")

typedef short bshort8 __attribute__((ext_vector_type(8)));
typedef float f32x16 __attribute__((ext_vector_type(16)));

union __align__(16) FragU { unsigned int u[4]; bshort8 v; };

__device__ __forceinline__ float frcp(float v){ return __builtin_amdgcn_rcpf(v); }
__device__ __forceinline__ float frsq(float v){ return __builtin_amdgcn_rsqf(v); }
__device__ __forceinline__ float fsigm(float v){ return frcp(1.f+__expf(-v)); }
__device__ __forceinline__ float fsilu(float v){ return v*frcp(1.f+__expf(-v)); }
__device__ __forceinline__ float ftanh_(float v){
    float c = fminf(fmaxf(v, -15.f), 15.f);
    float e = __expf(2.f*c);
    return (e-1.f)*frcp(e+1.f);
}
__device__ __forceinline__ float fgelu(float v){
    float t = ftanh_(0.7978845608028654f*(v + 0.044715f*v*v*v));
    return 0.5f*v*(1.f+t);
}
__device__ __forceinline__ unsigned int pkbf(float a, float b){
    __hip_bfloat162 h = __float22bfloat162_rn(make_float2(a,b));
    return *reinterpret_cast<unsigned int*>(&h);
}
__device__ __forceinline__ unsigned short bfr(float f){
    __hip_bfloat16 h = __float2bfloat16(f);
    return *reinterpret_cast<unsigned short*>(&h);
}
__device__ __forceinline__ float lobf(unsigned int u){ return __uint_as_float(u<<16); }
__device__ __forceinline__ float hibf(unsigned int u){ return __uint_as_float(u & 0xFFFF0000u); }

__device__ __forceinline__ void load_wfrag(const float* __restrict__ W,
                                           const float* __restrict__ bias, float scale,
                                           int ncol, int lo, int hi, FragU& o0, FragU& o1){
    float t[16];
    #pragma unroll
    for (int sl=0; sl<2; sl++){
        #pragma unroll
        for (int r=0;r<8;r++){
            int h = 8*hi + r + 16*sl;
            float v = 0.f;
            if (lo < ncol){
                if (h < MM) v = W[h*ncol+lo]*scale;
                else if (h == MM) v = bias[lo]*scale;
            }
            t[sl*8+r] = v;
        }
    }
    #pragma unroll
    for (int p=0;p<4;p++){
        o0.u[p] = pkbf(t[2*p],   t[2*p+1]);
        o1.u[p] = pkbf(t[8+2*p], t[8+2*p+1]);
    }
}

__device__ __forceinline__ void asm_frag(const f32x16& d, int hi, FragU& s0, FragU& s1){
    unsigned int P[8], X[8];
    #pragma unroll
    for (int m=0;m<8;m++) P[m] = pkbf(d[2*m], d[2*m+1]);
    #pragma unroll
    for (int m=0;m<8;m++) X[m] = (unsigned int)__shfl_xor((int)P[m], 32, 64);
    s0.u[0] = hi ? X[2] : P[0];  s0.u[1] = hi ? X[3] : P[1];
    s0.u[2] = hi ? P[2] : X[0];  s0.u[3] = hi ? P[3] : X[1];
    s1.u[0] = hi ? X[6] : P[4];  s1.u[1] = hi ? X[7] : P[5];
    s1.u[2] = hi ? P[6] : X[4];  s1.u[3] = hi ? P[7] : X[5];
}

extern "C" __global__ void __launch_bounds__(256, 5)
net_kernel(const float* __restrict__ xg,
           const float* __restrict__ ln_g, const float* __restrict__ ln_b,
           const float* __restrict__ Wup_l, const float* __restrict__ bup_l,
           const float* __restrict__ Wup_r, const float* __restrict__ bup_r,
           const float* __restrict__ conv_w, const float* __restrict__ conv_b,
           const float* __restrict__ Wq, const float* __restrict__ bq,
           const float* __restrict__ Wk, const float* __restrict__ bk,
           const float* __restrict__ Wv, const float* __restrict__ bv,
           const float* __restrict__ Wif, const float* __restrict__ bif,
           const float* __restrict__ gn_g, const float* __restrict__ gn_b,
           const float* __restrict__ skip,
           const float* __restrict__ Wdown, const float* __restrict__ bdown,
           const float* __restrict__ s_ln_g, const float* __restrict__ s_ln_b,
           const float* __restrict__ sW, const float* __restrict__ sR, const float* __restrict__ sb,
           const float* __restrict__ s_gn_g, const float* __restrict__ s_gn_b,
           const float* __restrict__ sWup1, const float* __restrict__ sbup1,
           const float* __restrict__ sWup2, const float* __restrict__ sbup2,
           const float* __restrict__ sWdown, const float* __restrict__ sbdown,
           const float* __restrict__ fc1w, const float* __restrict__ fc1b,
           const float* __restrict__ fc3w, const float* __restrict__ fc3b,
           float* __restrict__ out)
{
    __shared__ __align__(16) float smAll[4*PB];
    const int tid  = threadIdx.x;
    const int wid  = tid >> 6;
    const int lane = tid & 63;
    const int b = blockIdx.x*4 + wid;
    float* sm = smAll + wid*PB;
    unsigned short* smu = reinterpret_cast<unsigned short*>(sm);
    char* smc = reinterpret_cast<char*>(sm);
    const float* xp = xg + (size_t)b * (SS*DD);

    const int lo = lane & 31, hi = lane >> 5;
    const int jq = lane % MM;
    const int gq = lane / MM;
    const bool act = lane < 56;
    const int jqi = act ? jq : 0;

    // ---- bf16 staging pads: cols 28..31 = (1,0,0,0); rows 30,31 = 0 ----
    if (lane < SS){
        *(uint2*)(smc + CQ*4 + lane*80 + 56) = make_uint2(0x3F80u, 0u);
        *(uint2*)(smc + UE*4 + lane*80 + 56) = make_uint2(0x3F80u, 0u);
    }
    if (lane < 20){
        *(uint2*)(smc + CQ*4 + 30*80 + lane*8) = make_uint2(0u,0u);
        *(uint2*)(smc + UE*4 + 30*80 + lane*8) = make_uint2(0u,0u);
    }

    // ---- Phase A: LN1 -> xn (HX fp32) ----
    if (lane < SS){
        float xv[DD];
        const float2* xr = (const float2*)(xp + lane*DD);
        float s=0.f, s2=0.f;
        #pragma unroll
        for (int u=0;u<7;u++){ float2 f=xr[u]; xv[2*u]=f.x; xv[2*u+1]=f.y; s+=f.x+f.y; s2+=f.x*f.x+f.y*f.y; }
        float mu=s*(1.f/DD), var=s2*(1.f/DD)-mu*mu, rsg=frsq(var+1e-5f);
        #pragma unroll
        for (int d=0; d<DD; d++) sm[HX+lane*DD+d] = (xv[d]-mu)*rsg*ln_g[d]+ln_b[d];
    }
    WSYNC();

    // ---- Phase B+C fused: ul in regs -> ul bf16 (UE) + conv/silu -> c bf16 (CQ) ----
    {
        float wl[DD], cw[4];
        float blr = bup_l[jqi], cbr = conv_b[jqi];
        #pragma unroll
        for (int d=0; d<DD; d++) wl[d] = Wup_l[d*MM+jqi];
        #pragma unroll
        for (int k=0; k<4; k++) cw[k] = conv_w[k*MM+jqi];

        float ulr[15];
        #pragma unroll
        for (int tt=0; tt<15; tt++){
            int t = gq*15+tt;
            float a = blr;
            if (act){
                const float2* xr = (const float2*)&sm[HX + t*DD];
                #pragma unroll
                for (int u=0;u<7;u++){ float2 f = xr[u]; a += f.x*wl[2*u] + f.y*wl[2*u+1]; }
                smu[UE*2 + t*40 + jq] = bfr(a);
            }
            ulr[tt] = a;
        }
        float u12 = __shfl(ulr[12], jq, 64);
        float u13 = __shfl(ulr[13], jq, 64);
        float u14 = __shfl(ulr[14], jq, 64);
        float gqf = (gq==1) ? 1.f : 0.f;
        #pragma unroll
        for (int tt=0; tt<15; tt++){
            int t = gq*15+tt;
            float h3, h2, h1;
            if (tt>=3){ h3=ulr[tt-3]; h2=ulr[tt-2]; h1=ulr[tt-1]; }
            else if (tt==2){ h3=gqf*u14; h2=ulr[0]; h1=ulr[1]; }
            else if (tt==1){ h3=gqf*u13; h2=gqf*u14; h1=ulr[0]; }
            else           { h3=gqf*u12; h2=gqf*u13; h1=gqf*u14; }
            float a = cbr + cw[0]*h3 + cw[1]*h2 + cw[2]*h1 + cw[3]*ulr[tt];
            if (act) smu[CQ*2 + t*40 + jq] = bfr(fsilu(a));
        }
    }
    WSYNC();

    // ---- gif = c(bf16) @ Wif + bif -> ST2 ----
    if (lane < SS*2){
        int t=lane>>1, gg=lane&1;
        float a = bif[gg];
        const uint2* cr = (const uint2*)(smc + CQ*4 + t*80);
        #pragma unroll
        for (int p=0;p<7;p++){
            uint2 cu = cr[p];
            a += lobf(cu.x)*Wif[(4*p)*2+gg]   + hibf(cu.x)*Wif[(4*p+1)*2+gg]
               + lobf(cu.y)*Wif[(4*p+2)*2+gg] + hibf(cu.y)*Wif[(4*p+3)*2+gg];
        }
        sm[ST2+lane]=a;
    }
    WSYNC();

    // ---- D3: gate pre-scan -> EA, ECM (pads 30,31 = 0) ----
    if (lane < SS){
        float i_ = sm[ST2+2*lane], f_ = sm[ST2+2*lane+1];
        float F = f_, v;
        v = __shfl_up(F,1,64);  if (lane>=1)  F += v;
        v = __shfl_up(F,2,64);  if (lane>=2)  F += v;
        v = __shfl_up(F,4,64);  if (lane>=4)  F += v;
        v = __shfl_up(F,8,64);  if (lane>=8)  F += v;
        v = __shfl_up(F,16,64); if (lane>=16) F += v;
        float a = i_ - F;
        float cm = a;
        v = __shfl_up(cm,1,64);  if (lane>=1)  cm = fmaxf(cm,v);
        v = __shfl_up(cm,2,64);  if (lane>=2)  cm = fmaxf(cm,v);
        v = __shfl_up(cm,4,64);  if (lane>=4)  cm = fmaxf(cm,v);
        v = __shfl_up(cm,8,64);  if (lane>=8)  cm = fmaxf(cm,v);
        v = __shfl_up(cm,16,64); if (lane>=16) cm = fmaxf(cm,v);
        cm = fmaxf(cm, 0.f);
        sm[EA+lane]  = __expf(a);
        sm[ECM+lane] = __expf(-cm);
    } else if (lane < 32){
        sm[EA+lane] = 0.f; sm[ECM+lane] = 0.f;
    }
    WSYNC();

    // ---- silu(ur) precompute, pairwise pack (2 live fp32; 8 packed regs) ----
    unsigned int urp[8];
    {
        float wr[DD], brr = bup_r[jqi];
        #pragma unroll
        for (int d=0;d<DD;d++) wr[d]=Wup_r[d*MM+jqi];
        #pragma unroll
        for (int p=0; p<8; p++){
            float a0 = brr, a1 = brr;
            if (act){
                int t = gq*15 + 2*p;
                const float2* xr = (const float2*)&sm[HX + t*DD];
                #pragma unroll
                for (int u=0;u<7;u++){ float2 f=xr[u]; a0 += f.x*wr[2*u]+f.y*wr[2*u+1]; }
                if (p < 7){
                    const float2* xr2 = (const float2*)&sm[HX + (t+1)*DD];
                    #pragma unroll
                    for (int u=0;u<7;u++){ float2 f=xr2[u]; a1 += f.x*wr[2*u]+f.y*wr[2*u+1]; }
                }
            }
            urp[p] = pkbf(fsilu(a0), fsilu(a1));
        }
    }
    WSYNC();

    // ================= MFMA section: sequenced accumulators =================
    {
        FragU cf0 = *(const FragU*)(smc + CQ*4 + lo*80 + hi*16);
        FragU cf1 = *(const FragU*)(smc + CQ*4 + lo*80 + hi*16 + 32);

        FragU eq0, eq1, ek0, ek1;
        {
            FragU wq0, wq1;
            load_wfrag(Wq, bq, 1.f, MM, lo, hi, wq0, wq1);
            f32x16 aq = {};
            aq = __builtin_amdgcn_mfma_f32_32x32x16_bf16(wq0.v, cf0.v, aq, 0,0,0);
            aq = __builtin_amdgcn_mfma_f32_32x32x16_bf16(wq1.v, cf1.v, aq, 0,0,0);
            asm_frag(aq, hi, eq0, eq1);
        }
        {
            const float rs28 = 0.18898223650461363f;
            FragU wk0, wk1;
            load_wfrag(Wk, bk, rs28, MM, lo, hi, wk0, wk1);
            f32x16 ak = {};
            ak = __builtin_amdgcn_mfma_f32_32x32x16_bf16(wk0.v, cf0.v, ak, 0,0,0);
            ak = __builtin_amdgcn_mfma_f32_32x32x16_bf16(wk1.v, cf1.v, ak, 0,0,0);
            asm_frag(ak, hi, ek0, ek1);
        }
        FragU fa0, fa1;
        {
            f32x16 es = {};
            es = __builtin_amdgcn_mfma_f32_32x32x16_bf16(ek0.v, eq0.v, es, 0,0,0);
            es = __builtin_amdgcn_mfma_f32_32x32x16_bf16(ek1.v, eq1.v, es, 0,0,0);
            float ecmt = sm[ECM + lo];
            #pragma unroll
            for (int g=0; g<16; g++){
                int srow = (g&3) + 8*(g>>2) + 4*hi;
                float w = sm[EA + srow] * ecmt;
                es[g] = (srow <= lo) ? es[g]*w : 0.f;
            }
            asm_frag(es, hi, fa0, fa1);
        }
        FragU vb0, vb1;
        {
            FragU wv0, wv1;
            load_wfrag(Wv, bv, 1.f, MM, lo, hi, wv0, wv1);
            FragU uf0 = *(const FragU*)(smc + UE*4 + lo*80 + hi*16);
            FragU uf1 = *(const FragU*)(smc + UE*4 + lo*80 + hi*16 + 32);
            f32x16 av = {};
            av = __builtin_amdgcn_mfma_f32_32x32x16_bf16(uf0.v, wv0.v, av, 0,0,0);
            av = __builtin_amdgcn_mfma_f32_32x32x16_bf16(uf1.v, wv1.v, av, 0,0,0);
            asm_frag(av, hi, vb0, vb1);
        }
        if (lo == MM){
            const unsigned int ONE2 = 0x3F803F80u;
            vb0.u[0]=ONE2; vb0.u[1]=ONE2; vb0.u[2]=ONE2; vb0.u[3]=ONE2;
            vb1.u[0]=ONE2; vb1.u[1]=ONE2; vb1.u[2]=ONE2; vb1.u[3]= hi ? 0u : ONE2;
        }
        f32x16 hacc = {};
        hacc = __builtin_amdgcn_mfma_f32_32x32x16_bf16(fa0.v, vb0.v, hacc, 0,0,0);
        hacc = __builtin_amdgcn_mfma_f32_32x32x16_bf16(fa1.v, vb1.v, hacc, 0,0,0);

        // h -> HX bf16 stride29 (xn dead); trow<30, lo<29
        #pragma unroll
        for (int g=0; g<16; g++){
            int trow = (g&3) + 8*(g>>2) + 4*hi;
            if (lo < 29 && trow < SS) smu[HX*2 + trow*29 + lo] = bfr(hacc[g]);
        }
    }
    WSYNC();

    // ---- VALU preloads for G/L ----
    const int dq  = lane % DD;
    const int g4  = lane / DD;
    const int dqi = act ? dq : 0;
    float skr=skip[jqi], ggr=gn_g[jqi], gbr=gn_b[jqi];
    float swd0 = sWdown[0*DD+dqi], swd1 = sWdown[1*DD+dqi], swd2 = sWdown[2*DD+dqi];
    float sbd  = sbdown[dqi];

    // ---- Phase G0: per-t stats (h bf16; rowsum at col 28) ----
    if (lane < SS){
        float s=0.f,s2=0.f;
        #pragma unroll
        for (int u=0;u<MM;u++){
            float v = lobf((unsigned int)smu[HX*2 + lane*29 + u]);
            s+=v; s2+=v*v;
        }
        float rsum = lobf((unsigned int)smu[HX*2 + lane*29 + MM]);
        float inv = frcp(fmaxf(fabsf(rsum), 1.f));
        float mu=s*(1.f/MM), var=s2*(1.f/MM)-mu*mu;
        sm[ST2+lane*2]   = mu*inv;
        sm[ST2+lane*2+1] = frsq(var*inv*inv + 1e-5f);
        sm[ECM+lane]     = inv;
    }
    WSYNC();

    // ---- Phase G: e = (hn + skip*c)*silu_ur -> e bf16 (UE) ----
    #pragma unroll
    for (int tt=0;tt<15;tt++){
        int t=gq*15+tt;
        if (act){
            float inv = sm[ECM+t];
            float hv = lobf((unsigned int)smu[HX*2 + t*29 + jq])*inv;
            float hn = (hv-sm[ST2+t*2])*sm[ST2+t*2+1]*ggr + gbr;
            float cv = lobf((unsigned int)smu[CQ*2 + t*40 + jq]);
            float h2 = hn + skr*cv;
            float slu = (tt&1) ? hibf(urp[tt>>1]) : lobf(urp[tt>>1]);
            smu[UE*2 + t*40 + jq] = bfr(h2 * slu);
        }
    }
    WSYNC();

    // ---- Phase H (MFMA): y_m = e @ WdownAug + x -> HX fp32 (h dead) ----
    {
        FragU wd0, wd1;
        load_wfrag(Wdown, bdown, 1.f, DD, lo, hi, wd0, wd1);
        FragU ef0 = *(const FragU*)(smc + UE*4 + lo*80 + hi*16);
        FragU ef1 = *(const FragU*)(smc + UE*4 + lo*80 + hi*16 + 32);
        f32x16 ym = {};
        ym = __builtin_amdgcn_mfma_f32_32x32x16_bf16(ef0.v, wd0.v, ym, 0,0,0);
        ym = __builtin_amdgcn_mfma_f32_32x32x16_bf16(ef1.v, wd1.v, ym, 0,0,0);
        #pragma unroll
        for (int g=0; g<16; g++){
            int trow = (g&3) + 8*(g>>2) + 4*hi;
            if (lo < DD && trow < SS) sm[HX + trow*DD + lo] = ym[g] + xp[trow*DD + lo];
        }
    }
    WSYNC();

    // ---- Phase I: sLSTM LN -> yn fp32 into CQ (c dead) ----
    if (lane < SS){
        const float2* yr=(const float2*)&sm[HX+lane*DD];
        float yv[DD];
        float s=0.f,s2=0.f;
        #pragma unroll
        for (int u=0;u<7;u++){ float2 f=yr[u]; yv[2*u]=f.x; yv[2*u+1]=f.y; s+=f.x+f.y; s2+=f.x*f.x+f.y*f.y; }
        float mu=s*(1.f/DD), var=s2*(1.f/DD)-mu*mu, rs=frsq(var+1e-5f);
        #pragma unroll
        for (int d=0;d<DD;d++)
            sm[CQ+lane*DD+d] = (yv[d]-mu)*rs*s_ln_g[d] + s_ln_b[d];
    }
    WSYNC();

    // ---- Phase J: gx = yn @ sW + sb -> UE (e dead) ----
    for (int idx=lane; idx<SS*8; idx+=64){
        int t=idx>>3, gg=idx&7;
        float a=sb[gg];
        const float2* yr = (const float2*)&sm[CQ+t*DD];
        #pragma unroll
        for (int u=0;u<7;u++){
            float2 f=yr[u];
            a += f.x*sW[(2*u)*8+gg] + f.y*sW[(2*u+1)*8+gg];
        }
        sm[UE+idx]=a;
    }
    WSYNC();

    // ---- Phase K: sLSTM scan (rolled; lane0 writes hs -> ST2) ----
    {
        float R0[8], R1[8];
        #pragma unroll
        for (int g=0; g<8; g++){ R0[g]=sR[g]; R1[g]=sR[8+g]; }
        float h0=0.f,h1=0.f,c0=0.f,c1=0.f,n0=0.f,n1=0.f,m0=0.f,m1=0.f;
        const float2* gr = (const float2*)&sm[UE];
        float2 A0=gr[0], A1=gr[1], A2=gr[2], A3=gr[3];
        #pragma unroll 1
        for (int t=0; t<SS; t++){
            float2 N0,N1,N2,N3;
            if (t < SS-1){
                const float2* nx = (const float2*)&sm[UE+(t+1)*8];
                N0=nx[0]; N1=nx[1]; N2=nx[2]; N3=nx[3];
            }
            float g0=A0.x+h0*R0[0]+h1*R1[0], g1=A0.y+h0*R0[1]+h1*R1[1];
            float g2=A1.x+h0*R0[2]+h1*R1[2], g3=A1.y+h0*R0[3]+h1*R1[3];
            float g4v=A2.x+h0*R0[4]+h1*R1[4], g5=A2.y+h0*R0[5]+h1*R1[5];
            float g6=A3.x+h0*R0[6]+h1*R1[6], g7=A3.y+h0*R0[7]+h1*R1[7];
            float z0=ftanh_(g0), z1=ftanh_(g1);
            float mn0=fmaxf(g4v+m0, g2), mn1=fmaxf(g5+m1, g3);
            float ie0=__expf(g2-mn0), ie1=__expf(g3-mn1);
            float fe0=__expf(g4v+m0-mn0), fe1=__expf(g5+m1-mn1);
            c0 = fe0*c0 + ie0*z0;  c1 = fe1*c1 + ie1*z1;
            n0 = fe0*n0 + ie0;     n1 = fe1*n1 + ie1;
            h0 = c0*frcp((1.f+__expf(-g6))*n0);
            h1 = c1*frcp((1.f+__expf(-g7))*n1);
            m0 = mn0; m1 = mn1;
            if (lane == 0){ sm[ST2+t*2] = h0; sm[ST2+t*2+1] = h1; }
            A0=N0; A1=N1; A2=N2; A3=N3;
        }
    }
    WSYNC();

    // ---- Phase L0: per-t u-values -> UE (gx dead) ----
    if (lane < SS){
        float a0 = sm[ST2+lane*2], a1 = sm[ST2+lane*2+1];
        float mu = 0.5f*(a0+a1);
        float d0 = a0-mu, d1 = a1-mu;
        float var = 0.5f*(d0*d0 + d1*d1);
        float rsg = frsq(var + 1e-5f);
        float hn0 = d0*rsg*s_gn_g[0] + s_gn_b[0];
        float hn1 = d1*rsg*s_gn_g[1] + s_gn_b[1];
        #pragma unroll
        for (int u3=0; u3<3; u3++){
            float p1 = hn0*sWup1[u3] + hn1*sWup1[3+u3] + sbup1[u3];
            float p2 = hn0*sWup2[u3] + hn1*sWup2[3+u3] + sbup2[u3];
            sm[UE + lane*3 + u3] = fgelu(p1)*p2;
        }
    }
    WSYNC();

    // ---- Phase L: y_s + tanh -> CQ (yn dead) ----
    #pragma unroll
    for (int tt=0; tt<8; tt++){
        int t=g4*8+tt;
        if (act && t<SS){
            float acc = sbd + sm[HX+t*DD+dq]
                      + sm[UE+t*3]*swd0 + sm[UE+t*3+1]*swd1 + sm[UE+t*3+2]*swd2;
            sm[CQ+t*DD+dq] = ftanh_(acc);
        }
    }
    WSYNC();

    // ---- Phase M: head fc1(420->32,relu) + fc3(32->1) ----
    {
        int j = lane & 31, half = lane >> 5;
        const float2* tyr = (const float2*)&sm[CQ + half*210];
        float a = 0.f;
        const float* w1 = fc1w + (half*210)*32 + j;
        #pragma unroll 7
        for (int d2=0; d2<105; d2++){
            float2 tv = tyr[d2];
            a += tv.x*w1[(2*d2)*32] + tv.y*w1[(2*d2+1)*32];
        }
        a += __shfl_xor(a, 32, 64);
        a += fc1b[j];
        float r = fmaxf(a, 0.f);
        float p = r * fc3w[j];
        #pragma unroll
        for (int off=16; off>=1; off>>=1) p += __shfl_xor(p, off, 64);
        if (lane == 0) out[b] = p + fc3b[0];
    }
}

extern "C" void kernel_launch(void* const* d_in, const int* in_sizes, int n_in,
                              void* d_out, int out_size, void* d_ws, size_t ws_size,
                              hipStream_t stream) {
    const float* x      = (const float*)d_in[0];
    const float* ln_g   = (const float*)d_in[1];
    const float* ln_b   = (const float*)d_in[2];
    const float* Wup_l  = (const float*)d_in[3];
    const float* bup_l  = (const float*)d_in[4];
    const float* Wup_r  = (const float*)d_in[5];
    const float* bup_r  = (const float*)d_in[6];
    const float* conv_w = (const float*)d_in[7];
    const float* conv_b = (const float*)d_in[8];
    const float* Wq     = (const float*)d_in[9];
    const float* bq     = (const float*)d_in[10];
    const float* Wk     = (const float*)d_in[11];
    const float* bk     = (const float*)d_in[12];
    const float* Wv     = (const float*)d_in[13];
    const float* bv     = (const float*)d_in[14];
    const float* Wif    = (const float*)d_in[15];
    const float* bif    = (const float*)d_in[16];
    const float* gn_g   = (const float*)d_in[17];
    const float* gn_b   = (const float*)d_in[18];
    const float* skip   = (const float*)d_in[19];
    const float* Wdown  = (const float*)d_in[20];
    const float* bdown  = (const float*)d_in[21];
    const float* s_ln_g = (const float*)d_in[22];
    const float* s_ln_b = (const float*)d_in[23];
    const float* sW     = (const float*)d_in[24];
    const float* sR     = (const float*)d_in[25];
    const float* sb     = (const float*)d_in[26];
    const float* s_gn_g = (const float*)d_in[27];
    const float* s_gn_b = (const float*)d_in[28];
    const float* sWup1  = (const float*)d_in[29];
    const float* sbup1  = (const float*)d_in[30];
    const float* sWup2  = (const float*)d_in[31];
    const float* sbup2  = (const float*)d_in[32];
    const float* sWdown = (const float*)d_in[33];
    const float* sbdown = (const float*)d_in[34];
    const float* fc1w   = (const float*)d_in[35];
    const float* fc1b   = (const float*)d_in[36];
    const float* fc3w   = (const float*)d_in[37];
    const float* fc3b   = (const float*)d_in[38];
    float* out = (float*)d_out;

    hipLaunchKernelGGL(net_kernel, dim3(2048), dim3(256), 0, stream,
        x, ln_g, ln_b, Wup_l, bup_l, Wup_r, bup_r, conv_w, conv_b,
        Wq, bq, Wk, bk, Wv, bv, Wif, bif, gn_g, gn_b, skip, Wdown, bdown,
        s_ln_g, s_ln_b, sW, sR, sb, s_gn_g, s_gn_b,
        sWup1, sbup1, sWup2, sbup2, sWdown, sbdown,
        fc1w, fc1b, fc3w, fc3b, out);
}

// Round 19
// 88.855 us; speedup vs baseline: 1.8929x; 1.0356x over previous
//
#include <hip/hip_runtime.h>
#include <hip/hip_bf16.h>

#define SS 30
#define DD 14
#define MM 28

// Per-batch LDS float offsets (PB = 1860 fl = 7,440 B; block = 4 batches = 29,760 B)
#define HX  0     // 452: xn fp32(420) -> h bf16 stride30 (900us) -> y_m fp32(420)
#define CQ  452   // 640: c bf16 32x40us -> yn fp32(420) -> tanh(y_s)(420)
#define UE  1092  // 640: ul bf16 -> e bf16 -> gx(240) -> UV(90)
#define ST2 1732  // 64: gif -> G0 stats stride2 -> hs(60)
#define EA  1796  // 32: exp(a_s), pads 30,31 = 0
#define ECM 1828  // 32: exp(-cm_t), pads = 0 -> inv (G0)
#define PB  1860

#define WSYNC() asm volatile("" ::: "memory")

typedef short bshort8 __attribute__((ext_vector_type(8)));
typedef float f32x16 __attribute__((ext_vector_type(16)));

union __align__(16) FragU { unsigned int u[4]; bshort8 v; };

__device__ __forceinline__ float frcp(float v){ return __builtin_amdgcn_rcpf(v); }
__device__ __forceinline__ float frsq(float v){ return __builtin_amdgcn_rsqf(v); }
__device__ __forceinline__ float fsigm(float v){ return frcp(1.f+__expf(-v)); }
__device__ __forceinline__ float fsilu(float v){ return v*frcp(1.f+__expf(-v)); }
__device__ __forceinline__ float ftanh_(float v){
    float c = fminf(fmaxf(v, -15.f), 15.f);
    float e = __expf(2.f*c);
    return (e-1.f)*frcp(e+1.f);
}
__device__ __forceinline__ float fgelu(float v){
    float t = ftanh_(0.7978845608028654f*(v + 0.044715f*v*v*v));
    return 0.5f*v*(1.f+t);
}
__device__ __forceinline__ unsigned int pkbf(float a, float b){
    __hip_bfloat162 h = __float22bfloat162_rn(make_float2(a,b));
    return *reinterpret_cast<unsigned int*>(&h);
}
__device__ __forceinline__ unsigned short bfr(float f){
    __hip_bfloat16 h = __float2bfloat16(f);
    return *reinterpret_cast<unsigned short*>(&h);
}
__device__ __forceinline__ float lobf(unsigned int u){ return __uint_as_float(u<<16); }
__device__ __forceinline__ float hibf(unsigned int u){ return __uint_as_float(u & 0xFFFF0000u); }

__device__ __forceinline__ void load_wfrag(const float* __restrict__ W,
                                           const float* __restrict__ bias, float scale,
                                           int ncol, int lo, int hi, FragU& o0, FragU& o1){
    float t[16];
    #pragma unroll
    for (int sl=0; sl<2; sl++){
        #pragma unroll
        for (int r=0;r<8;r++){
            int h = 8*hi + r + 16*sl;
            float v = 0.f;
            if (lo < ncol){
                if (h < MM) v = W[h*ncol+lo]*scale;
                else if (h == MM) v = bias[lo]*scale;
            }
            t[sl*8+r] = v;
        }
    }
    #pragma unroll
    for (int p=0;p<4;p++){
        o0.u[p] = pkbf(t[2*p],   t[2*p+1]);
        o1.u[p] = pkbf(t[8+2*p], t[8+2*p+1]);
    }
}

__device__ __forceinline__ void asm_frag(const f32x16& d, int hi, FragU& s0, FragU& s1){
    unsigned int P[8], X[8];
    #pragma unroll
    for (int m=0;m<8;m++) P[m] = pkbf(d[2*m], d[2*m+1]);
    #pragma unroll
    for (int m=0;m<8;m++) X[m] = (unsigned int)__shfl_xor((int)P[m], 32, 64);
    s0.u[0] = hi ? X[2] : P[0];  s0.u[1] = hi ? X[3] : P[1];
    s0.u[2] = hi ? P[2] : X[0];  s0.u[3] = hi ? P[3] : X[1];
    s1.u[0] = hi ? X[6] : P[4];  s1.u[1] = hi ? X[7] : P[5];
    s1.u[2] = hi ? P[6] : X[4];  s1.u[3] = hi ? P[7] : X[5];
}

extern "C" __global__ void __launch_bounds__(256, 5)
net_kernel(const float* __restrict__ xg,
           const float* __restrict__ ln_g, const float* __restrict__ ln_b,
           const float* __restrict__ Wup_l, const float* __restrict__ bup_l,
           const float* __restrict__ Wup_r, const float* __restrict__ bup_r,
           const float* __restrict__ conv_w, const float* __restrict__ conv_b,
           const float* __restrict__ Wq, const float* __restrict__ bq,
           const float* __restrict__ Wk, const float* __restrict__ bk,
           const float* __restrict__ Wv, const float* __restrict__ bv,
           const float* __restrict__ Wif, const float* __restrict__ bif,
           const float* __restrict__ gn_g, const float* __restrict__ gn_b,
           const float* __restrict__ skip,
           const float* __restrict__ Wdown, const float* __restrict__ bdown,
           const float* __restrict__ s_ln_g, const float* __restrict__ s_ln_b,
           const float* __restrict__ sW, const float* __restrict__ sR, const float* __restrict__ sb,
           const float* __restrict__ s_gn_g, const float* __restrict__ s_gn_b,
           const float* __restrict__ sWup1, const float* __restrict__ sbup1,
           const float* __restrict__ sWup2, const float* __restrict__ sbup2,
           const float* __restrict__ sWdown, const float* __restrict__ sbdown,
           const float* __restrict__ fc1w, const float* __restrict__ fc1b,
           const float* __restrict__ fc3w, const float* __restrict__ fc3b,
           float* __restrict__ out)
{
    __shared__ __align__(16) float smAll[4*PB];
    const int tid  = threadIdx.x;
    const int wid  = tid >> 6;
    const int lane = tid & 63;
    const int b = blockIdx.x*4 + wid;
    float* sm = smAll + wid*PB;
    unsigned short* smu = reinterpret_cast<unsigned short*>(sm);
    char* smc = reinterpret_cast<char*>(sm);
    const float* xp = xg + (size_t)b * (SS*DD);

    const int lo = lane & 31, hi = lane >> 5;
    const int jq = lane % MM;
    const int gq = lane / MM;
    const bool act = lane < 56;
    const int jqi = act ? jq : 0;

    // ---- bf16 staging pads: cols 28..31 = (1,0,0,0); rows 30,31 = 0 ----
    if (lane < SS){
        *(uint2*)(smc + CQ*4 + lane*80 + 56) = make_uint2(0x3F80u, 0u);
        *(uint2*)(smc + UE*4 + lane*80 + 56) = make_uint2(0x3F80u, 0u);
    }
    if (lane < 20){
        *(uint2*)(smc + CQ*4 + 30*80 + lane*8) = make_uint2(0u,0u);
        *(uint2*)(smc + UE*4 + 30*80 + lane*8) = make_uint2(0u,0u);
    }

    // ---- Phase A: LN1 -> xn (HX fp32) ----
    if (lane < SS){
        float xv[DD];
        const float2* xr = (const float2*)(xp + lane*DD);
        float s=0.f, s2=0.f;
        #pragma unroll
        for (int u=0;u<7;u++){ float2 f=xr[u]; xv[2*u]=f.x; xv[2*u+1]=f.y; s+=f.x+f.y; s2+=f.x*f.x+f.y*f.y; }
        float mu=s*(1.f/DD), var=s2*(1.f/DD)-mu*mu, rsg=frsq(var+1e-5f);
        #pragma unroll
        for (int d=0; d<DD; d++) sm[HX+lane*DD+d] = (xv[d]-mu)*rsg*ln_g[d]+ln_b[d];
    }
    WSYNC();

    // ---- Phase B+C fused: ul in regs -> ul bf16 (UE) + conv/silu -> c bf16 (CQ) ----
    {
        float wl[DD], cw[4];
        float blr = bup_l[jqi], cbr = conv_b[jqi];
        #pragma unroll
        for (int d=0; d<DD; d++) wl[d] = Wup_l[d*MM+jqi];
        #pragma unroll
        for (int k=0; k<4; k++) cw[k] = conv_w[k*MM+jqi];

        float ulr[15];
        #pragma unroll
        for (int tt=0; tt<15; tt++){
            int t = gq*15+tt;
            float a = blr;
            if (act){
                const float2* xr = (const float2*)&sm[HX + t*DD];
                #pragma unroll
                for (int u=0;u<7;u++){ float2 f = xr[u]; a += f.x*wl[2*u] + f.y*wl[2*u+1]; }
                smu[UE*2 + t*40 + jq] = bfr(a);
            }
            ulr[tt] = a;
        }
        float u12 = __shfl(ulr[12], jq, 64);
        float u13 = __shfl(ulr[13], jq, 64);
        float u14 = __shfl(ulr[14], jq, 64);
        float gqf = (gq==1) ? 1.f : 0.f;
        #pragma unroll
        for (int tt=0; tt<15; tt++){
            int t = gq*15+tt;
            float h3, h2, h1;
            if (tt>=3){ h3=ulr[tt-3]; h2=ulr[tt-2]; h1=ulr[tt-1]; }
            else if (tt==2){ h3=gqf*u14; h2=ulr[0]; h1=ulr[1]; }
            else if (tt==1){ h3=gqf*u13; h2=gqf*u14; h1=ulr[0]; }
            else           { h3=gqf*u12; h2=gqf*u13; h1=gqf*u14; }
            float a = cbr + cw[0]*h3 + cw[1]*h2 + cw[2]*h1 + cw[3]*ulr[tt];
            if (act) smu[CQ*2 + t*40 + jq] = bfr(fsilu(a));
        }
    }
    WSYNC();

    // ---- gif = c(bf16) @ Wif + bif -> ST2 ----
    if (lane < SS*2){
        int t=lane>>1, gg=lane&1;
        float a = bif[gg];
        const uint2* cr = (const uint2*)(smc + CQ*4 + t*80);
        #pragma unroll
        for (int p=0;p<7;p++){
            uint2 cu = cr[p];
            a += lobf(cu.x)*Wif[(4*p)*2+gg]   + hibf(cu.x)*Wif[(4*p+1)*2+gg]
               + lobf(cu.y)*Wif[(4*p+2)*2+gg] + hibf(cu.y)*Wif[(4*p+3)*2+gg];
        }
        sm[ST2+lane]=a;
    }
    WSYNC();

    // ---- D3: gate pre-scan -> EA, ECM (pads 30,31 = 0) ----
    if (lane < SS){
        float i_ = sm[ST2+2*lane], f_ = sm[ST2+2*lane+1];
        float F = f_, v;
        v = __shfl_up(F,1,64);  if (lane>=1)  F += v;
        v = __shfl_up(F,2,64);  if (lane>=2)  F += v;
        v = __shfl_up(F,4,64);  if (lane>=4)  F += v;
        v = __shfl_up(F,8,64);  if (lane>=8)  F += v;
        v = __shfl_up(F,16,64); if (lane>=16) F += v;
        float a = i_ - F;
        float cm = a;
        v = __shfl_up(cm,1,64);  if (lane>=1)  cm = fmaxf(cm,v);
        v = __shfl_up(cm,2,64);  if (lane>=2)  cm = fmaxf(cm,v);
        v = __shfl_up(cm,4,64);  if (lane>=4)  cm = fmaxf(cm,v);
        v = __shfl_up(cm,8,64);  if (lane>=8)  cm = fmaxf(cm,v);
        v = __shfl_up(cm,16,64); if (lane>=16) cm = fmaxf(cm,v);
        cm = fmaxf(cm, 0.f);
        sm[EA+lane]  = __expf(a);
        sm[ECM+lane] = __expf(-cm);
    } else if (lane < 32){
        sm[EA+lane] = 0.f; sm[ECM+lane] = 0.f;
    }
    WSYNC();

    // ---- silu(ur) precompute, pairwise pack (2 live fp32; 8 packed regs) ----
    unsigned int urp[8];
    {
        float wr[DD], brr = bup_r[jqi];
        #pragma unroll
        for (int d=0;d<DD;d++) wr[d]=Wup_r[d*MM+jqi];
        #pragma unroll
        for (int p=0; p<8; p++){
            float a0 = brr, a1 = brr;
            if (act){
                int t = gq*15 + 2*p;
                const float2* xr = (const float2*)&sm[HX + t*DD];
                #pragma unroll
                for (int u=0;u<7;u++){ float2 f=xr[u]; a0 += f.x*wr[2*u]+f.y*wr[2*u+1]; }
                if (p < 7){
                    const float2* xr2 = (const float2*)&sm[HX + (t+1)*DD];
                    #pragma unroll
                    for (int u=0;u<7;u++){ float2 f=xr2[u]; a1 += f.x*wr[2*u]+f.y*wr[2*u+1]; }
                }
            }
            urp[p] = pkbf(fsilu(a0), fsilu(a1));
        }
    }
    WSYNC();

    // ================= MFMA section: sequenced accumulators =================
    {
        FragU cf0 = *(const FragU*)(smc + CQ*4 + lo*80 + hi*16);
        FragU cf1 = *(const FragU*)(smc + CQ*4 + lo*80 + hi*16 + 32);

        FragU eq0, eq1, ek0, ek1;
        {
            FragU wq0, wq1;
            load_wfrag(Wq, bq, 1.f, MM, lo, hi, wq0, wq1);
            f32x16 aq = {};
            aq = __builtin_amdgcn_mfma_f32_32x32x16_bf16(wq0.v, cf0.v, aq, 0,0,0);
            aq = __builtin_amdgcn_mfma_f32_32x32x16_bf16(wq1.v, cf1.v, aq, 0,0,0);
            asm_frag(aq, hi, eq0, eq1);
        }
        {
            const float rs28 = 0.18898223650461363f;
            FragU wk0, wk1;
            load_wfrag(Wk, bk, rs28, MM, lo, hi, wk0, wk1);
            f32x16 ak = {};
            ak = __builtin_amdgcn_mfma_f32_32x32x16_bf16(wk0.v, cf0.v, ak, 0,0,0);
            ak = __builtin_amdgcn_mfma_f32_32x32x16_bf16(wk1.v, cf1.v, ak, 0,0,0);
            asm_frag(ak, hi, ek0, ek1);
        }
        FragU fa0, fa1;
        {
            f32x16 es = {};
            es = __builtin_amdgcn_mfma_f32_32x32x16_bf16(ek0.v, eq0.v, es, 0,0,0);
            es = __builtin_amdgcn_mfma_f32_32x32x16_bf16(ek1.v, eq1.v, es, 0,0,0);
            float ecmt = sm[ECM + lo];
            #pragma unroll
            for (int g=0; g<16; g++){
                int srow = (g&3) + 8*(g>>2) + 4*hi;
                float w = sm[EA + srow] * ecmt;
                es[g] = (srow <= lo) ? es[g]*w : 0.f;
            }
            asm_frag(es, hi, fa0, fa1);
        }
        FragU vb0, vb1;
        {
            FragU wv0, wv1;
            load_wfrag(Wv, bv, 1.f, MM, lo, hi, wv0, wv1);
            FragU uf0 = *(const FragU*)(smc + UE*4 + lo*80 + hi*16);
            FragU uf1 = *(const FragU*)(smc + UE*4 + lo*80 + hi*16 + 32);
            f32x16 av = {};
            av = __builtin_amdgcn_mfma_f32_32x32x16_bf16(uf0.v, wv0.v, av, 0,0,0);
            av = __builtin_amdgcn_mfma_f32_32x32x16_bf16(uf1.v, wv1.v, av, 0,0,0);
            asm_frag(av, hi, vb0, vb1);
        }
        if (lo == MM){
            const unsigned int ONE2 = 0x3F803F80u;
            vb0.u[0]=ONE2; vb0.u[1]=ONE2; vb0.u[2]=ONE2; vb0.u[3]=ONE2;
            vb1.u[0]=ONE2; vb1.u[1]=ONE2; vb1.u[2]=ONE2; vb1.u[3]= hi ? 0u : ONE2;
        }
        f32x16 hacc = {};
        hacc = __builtin_amdgcn_mfma_f32_32x32x16_bf16(fa0.v, vb0.v, hacc, 0,0,0);
        hacc = __builtin_amdgcn_mfma_f32_32x32x16_bf16(fa1.v, vb1.v, hacc, 0,0,0);

        // h -> HX bf16 stride30 (xn dead); trow<30, lo<29
        #pragma unroll
        for (int g=0; g<16; g++){
            int trow = (g&3) + 8*(g>>2) + 4*hi;
            if (lo < 29 && trow < SS) smu[HX*2 + trow*30 + lo] = bfr(hacc[g]);
        }
    }
    WSYNC();

    // ---- VALU preloads for G/L ----
    const int dq  = lane % DD;
    const int g4  = lane / DD;
    const int dqi = act ? dq : 0;
    float skr=skip[jqi], ggr=gn_g[jqi], gbr=gn_b[jqi];
    float swd0 = sWdown[0*DD+dqi], swd1 = sWdown[1*DD+dqi], swd2 = sWdown[2*DD+dqi];
    float sbd  = sbdown[dqi];

    // ---- Phase G0: per-t stats (h bf16 stride30; uint reads; rowsum col 28) ----
    if (lane < SS){
        const unsigned int* hr = (const unsigned int*)(smc + HX*4 + lane*60);
        float s=0.f,s2=0.f;
        #pragma unroll
        for (int u=0;u<14;u++){
            unsigned int w = hr[u];
            float v0 = lobf(w), v1 = hibf(w);
            s += v0+v1; s2 += v0*v0+v1*v1;
        }
        float rsum = lobf(hr[14]);
        float inv = frcp(fmaxf(fabsf(rsum), 1.f));
        float mu=s*(1.f/MM), var=s2*(1.f/MM)-mu*mu;
        sm[ST2+lane*2]   = mu*inv;
        sm[ST2+lane*2+1] = frsq(var*inv*inv + 1e-5f);
        sm[ECM+lane]     = inv;
    }
    WSYNC();

    // ---- Phase G: e = (hn + skip*c)*silu_ur -> e bf16 (UE) ----
    #pragma unroll
    for (int tt=0;tt<15;tt++){
        int t=gq*15+tt;
        if (act){
            float inv = sm[ECM+t];
            float hv = lobf((unsigned int)smu[HX*2 + t*30 + jq])*inv;
            float hn = (hv-sm[ST2+t*2])*sm[ST2+t*2+1]*ggr + gbr;
            float cv = lobf((unsigned int)smu[CQ*2 + t*40 + jq]);
            float h2 = hn + skr*cv;
            float slu = (tt&1) ? hibf(urp[tt>>1]) : lobf(urp[tt>>1]);
            smu[UE*2 + t*40 + jq] = bfr(h2 * slu);
        }
    }
    WSYNC();

    // ---- Phase H (MFMA): y_m = e @ WdownAug + x -> HX fp32 (h dead) ----
    {
        FragU wd0, wd1;
        load_wfrag(Wdown, bdown, 1.f, DD, lo, hi, wd0, wd1);
        FragU ef0 = *(const FragU*)(smc + UE*4 + lo*80 + hi*16);
        FragU ef1 = *(const FragU*)(smc + UE*4 + lo*80 + hi*16 + 32);
        f32x16 ym = {};
        ym = __builtin_amdgcn_mfma_f32_32x32x16_bf16(ef0.v, wd0.v, ym, 0,0,0);
        ym = __builtin_amdgcn_mfma_f32_32x32x16_bf16(ef1.v, wd1.v, ym, 0,0,0);
        #pragma unroll
        for (int g=0; g<16; g++){
            int trow = (g&3) + 8*(g>>2) + 4*hi;
            if (lo < DD && trow < SS) sm[HX + trow*DD + lo] = ym[g] + xp[trow*DD + lo];
        }
    }
    WSYNC();

    // ---- Phase I: sLSTM LN -> yn fp32 into CQ (c dead) ----
    if (lane < SS){
        const float2* yr=(const float2*)&sm[HX+lane*DD];
        float yv[DD];
        float s=0.f,s2=0.f;
        #pragma unroll
        for (int u=0;u<7;u++){ float2 f=yr[u]; yv[2*u]=f.x; yv[2*u+1]=f.y; s+=f.x+f.y; s2+=f.x*f.x+f.y*f.y; }
        float mu=s*(1.f/DD), var=s2*(1.f/DD)-mu*mu, rs=frsq(var+1e-5f);
        #pragma unroll
        for (int d=0;d<DD;d++)
            sm[CQ+lane*DD+d] = (yv[d]-mu)*rs*s_ln_g[d] + s_ln_b[d];
    }
    WSYNC();

    // ---- Phase J: gx = yn @ sW + sb -> UE (e dead) ----
    for (int idx=lane; idx<SS*8; idx+=64){
        int t=idx>>3, gg=idx&7;
        float a=sb[gg];
        const float2* yr = (const float2*)&sm[CQ+t*DD];
        #pragma unroll
        for (int u=0;u<7;u++){
            float2 f=yr[u];
            a += f.x*sW[(2*u)*8+gg] + f.y*sW[(2*u+1)*8+gg];
        }
        sm[UE+idx]=a;
    }
    WSYNC();

    // ---- Phase K: sLSTM scan (unroll 2; lane0 writes hs -> ST2) ----
    {
        float R0[8], R1[8];
        #pragma unroll
        for (int g=0; g<8; g++){ R0[g]=sR[g]; R1[g]=sR[8+g]; }
        float h0=0.f,h1=0.f,c0=0.f,c1=0.f,n0=0.f,n1=0.f,m0=0.f,m1=0.f;
        const float2* gr = (const float2*)&sm[UE];
        float2 A0=gr[0], A1=gr[1], A2=gr[2], A3=gr[3];
        #pragma unroll 2
        for (int t=0; t<SS; t++){
            float2 N0,N1,N2,N3;
            if (t < SS-1){
                const float2* nx = (const float2*)&sm[UE+(t+1)*8];
                N0=nx[0]; N1=nx[1]; N2=nx[2]; N3=nx[3];
            }
            float g0=A0.x+h0*R0[0]+h1*R1[0], g1=A0.y+h0*R0[1]+h1*R1[1];
            float g2=A1.x+h0*R0[2]+h1*R1[2], g3=A1.y+h0*R0[3]+h1*R1[3];
            float g4v=A2.x+h0*R0[4]+h1*R1[4], g5=A2.y+h0*R0[5]+h1*R1[5];
            float g6=A3.x+h0*R0[6]+h1*R1[6], g7=A3.y+h0*R0[7]+h1*R1[7];
            float z0=ftanh_(g0), z1=ftanh_(g1);
            float mn0=fmaxf(g4v+m0, g2), mn1=fmaxf(g5+m1, g3);
            float ie0=__expf(g2-mn0), ie1=__expf(g3-mn1);
            float fe0=__expf(g4v+m0-mn0), fe1=__expf(g5+m1-mn1);
            c0 = fe0*c0 + ie0*z0;  c1 = fe1*c1 + ie1*z1;
            n0 = fe0*n0 + ie0;     n1 = fe1*n1 + ie1;
            h0 = c0*frcp((1.f+__expf(-g6))*n0);
            h1 = c1*frcp((1.f+__expf(-g7))*n1);
            m0 = mn0; m1 = mn1;
            if (lane == 0){ sm[ST2+t*2] = h0; sm[ST2+t*2+1] = h1; }
            A0=N0; A1=N1; A2=N2; A3=N3;
        }
    }
    WSYNC();

    // ---- Phase L0: per-t u-values -> UE (gx dead) ----
    if (lane < SS){
        float a0 = sm[ST2+lane*2], a1 = sm[ST2+lane*2+1];
        float mu = 0.5f*(a0+a1);
        float d0 = a0-mu, d1 = a1-mu;
        float var = 0.5f*(d0*d0 + d1*d1);
        float rsg = frsq(var + 1e-5f);
        float hn0 = d0*rsg*s_gn_g[0] + s_gn_b[0];
        float hn1 = d1*rsg*s_gn_g[1] + s_gn_b[1];
        #pragma unroll
        for (int u3=0; u3<3; u3++){
            float p1 = hn0*sWup1[u3] + hn1*sWup1[3+u3] + sbup1[u3];
            float p2 = hn0*sWup2[u3] + hn1*sWup2[3+u3] + sbup2[u3];
            sm[UE + lane*3 + u3] = fgelu(p1)*p2;
        }
    }
    WSYNC();

    // ---- Phase L: y_s + tanh -> CQ (yn dead) ----
    #pragma unroll
    for (int tt=0; tt<8; tt++){
        int t=g4*8+tt;
        if (act && t<SS){
            float acc = sbd + sm[HX+t*DD+dq]
                      + sm[UE+t*3]*swd0 + sm[UE+t*3+1]*swd1 + sm[UE+t*3+2]*swd2;
            sm[CQ+t*DD+dq] = ftanh_(acc);
        }
    }
    WSYNC();

    // ---- Phase M: head fc1(420->32,relu) + fc3(32->1) ----
    {
        int j = lane & 31, half = lane >> 5;
        const float2* tyr = (const float2*)&sm[CQ + half*210];
        float a = 0.f;
        const float* w1 = fc1w + (half*210)*32 + j;
        #pragma unroll 15
        for (int d2=0; d2<105; d2++){
            float2 tv = tyr[d2];
            a += tv.x*w1[(2*d2)*32] + tv.y*w1[(2*d2+1)*32];
        }
        a += __shfl_xor(a, 32, 64);
        a += fc1b[j];
        float r = fmaxf(a, 0.f);
        float p = r * fc3w[j];
        #pragma unroll
        for (int off=16; off>=1; off>>=1) p += __shfl_xor(p, off, 64);
        if (lane == 0) out[b] = p + fc3b[0];
    }
}

extern "C" void kernel_launch(void* const* d_in, const int* in_sizes, int n_in,
                              void* d_out, int out_size, void* d_ws, size_t ws_size,
                              hipStream_t stream) {
    const float* x      = (const float*)d_in[0];
    const float* ln_g   = (const float*)d_in[1];
    const float* ln_b   = (const float*)d_in[2];
    const float* Wup_l  = (const float*)d_in[3];
    const float* bup_l  = (const float*)d_in[4];
    const float* Wup_r  = (const float*)d_in[5];
    const float* bup_r  = (const float*)d_in[6];
    const float* conv_w = (const float*)d_in[7];
    const float* conv_b = (const float*)d_in[8];
    const float* Wq     = (const float*)d_in[9];
    const float* bq     = (const float*)d_in[10];
    const float* Wk     = (const float*)d_in[11];
    const float* bk     = (const float*)d_in[12];
    const float* Wv     = (const float*)d_in[13];
    const float* bv     = (const float*)d_in[14];
    const float* Wif    = (const float*)d_in[15];
    const float* bif    = (const float*)d_in[16];
    const float* gn_g   = (const float*)d_in[17];
    const float* gn_b   = (const float*)d_in[18];
    const float* skip   = (const float*)d_in[19];
    const float* Wdown  = (const float*)d_in[20];
    const float* bdown  = (const float*)d_in[21];
    const float* s_ln_g = (const float*)d_in[22];
    const float* s_ln_b = (const float*)d_in[23];
    const float* sW     = (const float*)d_in[24];
    const float* sR     = (const float*)d_in[25];
    const float* sb     = (const float*)d_in[26];
    const float* s_gn_g = (const float*)d_in[27];
    const float* s_gn_b = (const float*)d_in[28];
    const float* sWup1  = (const float*)d_in[29];
    const float* sbup1  = (const float*)d_in[30];
    const float* sWup2  = (const float*)d_in[31];
    const float* sbup2  = (const float*)d_in[32];
    const float* sWdown = (const float*)d_in[33];
    const float* sbdown = (const float*)d_in[34];
    const float* fc1w   = (const float*)d_in[35];
    const float* fc1b   = (const float*)d_in[36];
    const float* fc3w   = (const float*)d_in[37];
    const float* fc3b   = (const float*)d_in[38];
    float* out = (float*)d_out;

    hipLaunchKernelGGL(net_kernel, dim3(2048), dim3(256), 0, stream,
        x, ln_g, ln_b, Wup_l, bup_l, Wup_r, bup_r, conv_w, conv_b,
        Wq, bq, Wk, bk, Wv, bv, Wif, bif, gn_g, gn_b, skip, Wdown, bdown,
        s_ln_g, s_ln_b, sW, sR, sb, s_gn_g, s_gn_b,
        sWup1, sbup1, sWup2, sbup2, sWdown, sbdown,
        fc1w, fc1b, fc3w, fc3b, out);
}